// Round 2
// baseline (7765.211 us; speedup 1.0000x reference)
//
#include <hip/hip_runtime.h>
#include <hip/hip_bf16.h>

// MLA absorbed causal attention, MI355X round 1: fp32 I/O (per reference dtypes),
// bf16 internal q_lat/c_kv (threshold has bf16 floor: 8*2^-7*1.05).
// d_out = [ y (2*2048*1024) | c_kv (2*2048*512) ] fp32.

using bf16 = __hip_bfloat16;
using u32  = unsigned int;

static constexpr int kB  = 2;
static constexpr int kT  = 2048;
static constexpr int kC  = 1024;
static constexpr int kNH = 16;
static constexpr int kHS = 64;
static constexpr int kL  = 512;   // QL == KVL == 512

__device__ inline float ldf(const float* p) { return *p; }
__device__ inline float ldf(const bf16* p)  { return __bfloat162float(*p); }
__device__ inline void  stf(float* p, float v) { *p = v; }
__device__ inline void  stf(bf16* p,  float v) { *p = __float2bfloat16(v); }

__device__ inline float2 bf2f2(u32 u) {
  float lo = __uint_as_float(u << 16);
  float hi = __uint_as_float(u & 0xffff0000u);
  return make_float2(lo, hi);
}
__device__ inline u32 f2bf2(float a, float b) {
  bf16 ha = __float2bfloat16(a), hb = __float2bfloat16(b);
  unsigned short ua, ub;
  __builtin_memcpy(&ua, &ha, 2);
  __builtin_memcpy(&ub, &hb, 2);
  return (u32)ua | ((u32)ub << 16);
}

// ---------------------------------------------------------------------------
// Generic tiled GEMM: C[m,n] = alpha * sum_k opA(m,k)*opB(k,n)
// TA: opA(m,k)=A[k*lda+m] else A[m*lda+k]; TB: opB(k,n)=B[n*ldb+k] else B[k*ldb+n]
// Batch via blockIdx.z decomposed as (z>>4, z&15) with (hi,lo) strides (nh=16).
// 64x64 tile, BK=16, 256 threads, 4x4 microtile. Requires M%64==N%64==K%16==0.
// ---------------------------------------------------------------------------
template<bool TA, bool TB, typename TAe, typename TBe, typename TCe>
__global__ __launch_bounds__(256)
void gemm_kernel(const TAe* __restrict__ A, int lda, long aHi, long aLo,
                 const TBe* __restrict__ Bm, int ldb, long bHi, long bLo,
                 TCe* __restrict__ Cm, int ldc, long cHi, long cLo,
                 int M, int N, int K, float alpha)
{
  const int z = blockIdx.z;
  A  += (long)(z >> 4) * aHi + (long)(z & 15) * aLo;
  Bm += (long)(z >> 4) * bHi + (long)(z & 15) * bLo;
  Cm += (long)(z >> 4) * cHi + (long)(z & 15) * cLo;

  // 72-float row stride: rows 16B-aligned (288 B) for float4 reads, stride%32=8
  __shared__ __align__(16) float As[16][72];
  __shared__ __align__(16) float Bs[16][72];

  const int tid = threadIdx.x;
  const int tx = tid & 15, ty = tid >> 4;
  const int m0 = blockIdx.x * 64, n0 = blockIdx.y * 64;
  float acc[4][4] = {};

  for (int k0 = 0; k0 < K; k0 += 16) {
    if (TA) {
      for (int l = tid; l < 1024; l += 256) {      // coalesced over m
        int k = l >> 6, m = l & 63;
        As[k][m] = ldf(&A[(long)(k0 + k) * lda + (m0 + m)]);
      }
    } else {
      for (int l = tid; l < 1024; l += 256) {      // 16-element runs over k
        int m = l >> 4, k = l & 15;
        As[k][m] = ldf(&A[(long)(m0 + m) * lda + (k0 + k)]);
      }
    }
    if (TB) {
      for (int l = tid; l < 1024; l += 256) {
        int n = l >> 4, k = l & 15;
        Bs[k][n] = ldf(&Bm[(long)(n0 + n) * ldb + (k0 + k)]);
      }
    } else {
      for (int l = tid; l < 1024; l += 256) {
        int k = l >> 6, n = l & 63;
        Bs[k][n] = ldf(&Bm[(long)(k0 + k) * ldb + (n0 + n)]);
      }
    }
    __syncthreads();
#pragma unroll
    for (int kk = 0; kk < 16; ++kk) {
      float4 av = *(const float4*)&As[kk][ty * 4];   // broadcast across tx
      float4 bv = *(const float4*)&Bs[kk][tx * 4];   // 2-way alias (free)
      float a[4] = {av.x, av.y, av.z, av.w};
      float b[4] = {bv.x, bv.y, bv.z, bv.w};
#pragma unroll
      for (int i = 0; i < 4; ++i)
#pragma unroll
        for (int j = 0; j < 4; ++j)
          acc[i][j] += a[i] * b[j];
    }
    __syncthreads();
  }
#pragma unroll
  for (int i = 0; i < 4; ++i)
#pragma unroll
    for (int j = 0; j < 4; ++j)
      stf(&Cm[(long)(m0 + ty*4 + i) * ldc + (n0 + tx*4 + j)], alpha * acc[i][j]);
}

// fp32 -> bf16 cast (c_kv internal copy for attention K/V). n multiple of 1024.
__global__ __launch_bounds__(256)
void cast_kernel(const float* __restrict__ src, bf16* __restrict__ dst, int n)
{
  int i = (blockIdx.x * 256 + threadIdx.x) * 4;
  if (i < n) {
    float4 v = *(const float4*)(src + i);
    u32 lo = f2bf2(v.x, v.y), hi = f2bf2(v.z, v.w);
    *(uint2*)((u32*)dst + i / 2) = make_uint2(lo, hi);
  }
}

// ---------------------------------------------------------------------------
// Flash attention over latent KV. One WG = (b, h, 32-query tile), 256 threads.
// Streams 16-key tiles of c_kv (bf16 internal copy), online softmax.
// q_lat rows are scaled by 1/8 already (folded into k_eff).
// Writes y_lat IN PLACE over q_lat. LDS total ~51 KB (<64 KB/WG limit).
// Thread map: r = tid&31 (query row), g = tid>>5 (0..7, 64-col group of O).
// ---------------------------------------------------------------------------
#define TQ 32
#define TK 16
#define LKP 520   // padded Ks row (1040 B: 16B-aligned rows; u32 stride 260, %32=4)

__global__ __launch_bounds__(256)
void flash_attn(bf16* __restrict__ qlat, const bf16* __restrict__ ckv)
{
  const int qt = blockIdx.x;
  const int h  = blockIdx.y;
  const int b  = blockIdx.z;
  const int tid = threadIdx.x;
  const int r = tid & 31;
  const int g = tid >> 5;

  __shared__ u32 Qt[kL/2][TQ];                 // transposed packed-bf16 Q: 32 KB
  __shared__ __align__(16) bf16 Ks[TK][LKP];   // 16.25 KB
  __shared__ float Ss[TQ][TK + 1];             // padded: banks (17r+k)%32 distinct
  __shared__ float mrow[TQ], lrow[TQ], arow[TQ];

  bf16* qbase = qlat + (((long)(b * kNH + h)) * kT + (long)qt * TQ) * kL;

  { // load Q tile once, transposed (32-way write conflicts, amortized over WG)
    const u32* src = (const u32*)qbase;        // 32 rows x 256 u32 contiguous
    for (int idx = tid; idx < TQ * (kL/2); idx += 256) {
      int rr = idx >> 8, l2 = idx & 255;
      Qt[l2][rr] = src[idx];
    }
  }
  if (tid < TQ) { mrow[tid] = -1e30f; lrow[tid] = 0.0f; }

  float O[64];
#pragma unroll
  for (int c = 0; c < 64; ++c) O[c] = 0.0f;

  const int q0 = qt * TQ;
  const int nkt = 2 * qt + 2;                  // key tiles 0 .. (q0+31)/16
  for (int kt = 0; kt < nkt; ++kt) {
    const int k0 = kt * TK;
    __syncthreads();                           // Ks/Ss reuse vs prev PV
    {
      const uint4* src = (const uint4*)(ckv + ((long)b * kT + k0) * kL);
      for (int idx = tid; idx < TK * (kL/8); idx += 256) {   // 1024 x uint4
        int rr = idx >> 6, c = idx & 63;
        ((uint4*)&Ks[rr][0])[c] = src[idx];
      }
    }
    __syncthreads();

    // scores: thread (r,g) -> keys k = g and g+8 (Qt read conflict-free)
    float s0 = 0.f, s1 = 0.f;
    {
      const u32* k0p = (const u32*)&Ks[g][0];
      const u32* k1p = (const u32*)&Ks[g + 8][0];
#pragma unroll 4
      for (int l2 = 0; l2 < kL/2; ++l2) {
        float2 q = bf2f2(Qt[l2][r]);
        float2 a = bf2f2(k0p[l2]);
        float2 c = bf2f2(k1p[l2]);
        s0 += q.x * a.x + q.y * a.y;
        s1 += q.x * c.x + q.y * c.y;
      }
    }
    Ss[r][g]     = (k0 + g     <= q0 + r) ? s0 : -1e30f;
    Ss[r][g + 8] = (k0 + g + 8 <= q0 + r) ? s1 : -1e30f;
    __syncthreads();

    if (tid < TQ) {  // per-row online softmax update (serial over 16 keys)
      float mold = mrow[tid];
      float mx = mold;
#pragma unroll
      for (int k = 0; k < TK; ++k) mx = fmaxf(mx, Ss[tid][k]);
      float al = __expf(mold - mx);
      float sum = 0.f;
#pragma unroll
      for (int k = 0; k < TK; ++k) {
        float p = __expf(Ss[tid][k] - mx);
        Ss[tid][k] = p;
        sum += p;
      }
      mrow[tid] = mx;
      lrow[tid] = lrow[tid] * al + sum;
      arow[tid] = al;
    }
    __syncthreads();

    // PV: O[r][g*64 + c] += p * V  (V = same c_kv tile)
    float al = arow[r];
#pragma unroll
    for (int c = 0; c < 64; ++c) O[c] *= al;
    for (int k = 0; k < TK; ++k) {
      float p = Ss[r][k];                       // banks distinct (stride 17)
      const u32* vrow = (const u32*)&Ks[k][0] + g * 32;  // 2-way alias (free)
#pragma unroll
      for (int c2 = 0; c2 < 32; ++c2) {
        float2 v = bf2f2(vrow[c2]);
        O[2*c2]     += p * v.x;
        O[2*c2 + 1] += p * v.y;
      }
    }
  }

  const float inv = 1.0f / lrow[r];             // >=1 always (diag key)
  u32* dst = (u32*)(qbase + (long)r * kL) + g * 32;
#pragma unroll
  for (int c2 = 0; c2 < 32; ++c2)
    dst[c2] = f2bf2(O[2*c2] * inv, O[2*c2 + 1] * inv);
}

// ---------------------------------------------------------------------------
extern "C" void kernel_launch(void* const* d_in, const int* in_sizes, int n_in,
                              void* d_out, int out_size, void* d_ws, size_t ws_size,
                              hipStream_t stream)
{
  const float* x     = (const float*)d_in[0];
  const float* W_dq  = (const float*)d_in[1];
  const float* W_uq  = (const float*)d_in[2];
  const float* W_dkv = (const float*)d_in[3];
  const float* W_uk  = (const float*)d_in[4];
  const float* W_uv  = (const float*)d_in[5];
  const float* W_o   = (const float*)d_in[6];

  float* y_out   = (float*)d_out;
  float* ckv_out = y_out + (long)kB * kT * kC;  // output 1 (fp32)

  // workspace layout (~98 MB)
  char*  ws     = (char*)d_ws;
  float* tmp_qk = (float*)(ws + 0);             // 512x512          1 MB
  float* k_eff  = (float*)(ws + 1048576);       // 1024x512 (/8)    2 MB
  float* v_eff  = (float*)(ws + 3145728);       // 512x1024         2 MB
  float* q_low  = (float*)(ws + 5242880);       // 4096x512         8 MB
  float* qfull  = (float*)(ws + 13631488);      // 4096x1024       16 MB
  bf16*  ckv_b  = (bf16*)(ws + 30408704);       // [2,2048,512]     4 MB (attn K/V)
  bf16*  q_lat  = (bf16*)(ws + 34603008);       // [2,16,2048,512] 64 MB (y_lat in place)

  const dim3 blk(256);
  const long TC = (long)kT * kC, TL = (long)kT * kL;

  // tmp_qk = W_uq^T @ W_uk
  gemm_kernel<true, false, float, float, float><<<dim3(8, 8, 1), blk, 0, stream>>>(
      W_uq, 512, 0, 0, W_uk, 512, 0, 0, tmp_qk, 512, 0, 0, 512, 512, 1024, 1.0f);
  // k_eff = W_dq^T @ tmp_qk * (1/sqrt(hs))
  gemm_kernel<true, false, float, float, float><<<dim3(16, 8, 1), blk, 0, stream>>>(
      W_dq, 1024, 0, 0, tmp_qk, 512, 0, 0, k_eff, 512, 0, 0, 1024, 512, 512, 0.125f);
  // v_eff[l,j] = sum_c W_uv[c,l] * W_o[j,c]
  gemm_kernel<true, true, float, float, float><<<dim3(8, 16, 1), blk, 0, stream>>>(
      W_uv, 512, 0, 0, W_o, 1024, 0, 0, v_eff, 1024, 0, 0, 512, 1024, 1024, 1.0f);
  // q_low = x @ W_dq^T
  gemm_kernel<false, true, float, float, float><<<dim3(64, 8, 1), blk, 0, stream>>>(
      x, 1024, 0, 0, W_dq, 1024, 0, 0, q_low, 512, 0, 0, 4096, 512, 1024, 1.0f);
  // qfull = q_low @ W_uq^T
  gemm_kernel<false, true, float, float, float><<<dim3(64, 16, 1), blk, 0, stream>>>(
      q_low, 512, 0, 0, W_uq, 512, 0, 0, qfull, 1024, 0, 0, 4096, 1024, 512, 1.0f);
  // c_kv = x @ W_dkv^T  -> fp32 directly into d_out tail (output 1)
  gemm_kernel<false, true, float, float, float><<<dim3(64, 8, 1), blk, 0, stream>>>(
      x, 1024, 0, 0, W_dkv, 1024, 0, 0, ckv_out, 512, 0, 0, 4096, 512, 1024, 1.0f);
  // bf16 internal copy of c_kv for attention K/V
  cast_kernel<<<dim3((kB * kT * kL) / 1024), blk, 0, stream>>>(
      ckv_out, ckv_b, kB * kT * kL);
  // q_lat[b,h] = qfull[b, :, h-slice] @ k_eff[h]   (batched over z = b*16+h)
  gemm_kernel<false, false, float, float, bf16><<<dim3(32, 8, 32), blk, 0, stream>>>(
      qfull, 1024, TC, 64,
      k_eff, 512, 0, (long)kHS * kL,
      q_lat, 512, (long)kNH * TL, TL,
      2048, 512, 64, 1.0f);
  // flash attention: q_lat -> y_lat (in place)
  flash_attn<<<dim3(kT / TQ, kNH, kB), blk, 0, stream>>>(q_lat, ckv_b);
  // y[b, :, h-slice] = y_lat[b,h] @ v_eff[:, h-slice]
  gemm_kernel<false, false, bf16, float, float><<<dim3(32, 1, 32), blk, 0, stream>>>(
      q_lat, 512, (long)kNH * TL, TL,
      v_eff, 1024, 0, 64,
      y_out, 1024, TC, 64,
      2048, 64, 512, 1.0f);

  (void)in_sizes; (void)n_in; (void)out_size; (void)ws_size;
}

// Round 3
// 2316.997 us; speedup vs baseline: 3.3514x; 3.3514x over previous
//
#include <hip/hip_runtime.h>
#include <hip/hip_bf16.h>

// MLA absorbed causal attention, MI355X round 2: MFMA flash attention.
// fp32 I/O, bf16 internals. d_out = [ y (2*2048*1024) | c_kv (2*2048*512) ] fp32.

using bf16 = __hip_bfloat16;
using u32  = unsigned int;
using short8 = __attribute__((ext_vector_type(8))) short;   // 8 bf16 (4 VGPRs)
using f4     = __attribute__((ext_vector_type(4))) float;   // MFMA accumulator

static constexpr int kB  = 2;
static constexpr int kT  = 2048;
static constexpr int kC  = 1024;
static constexpr int kNH = 16;
static constexpr int kHS = 64;
static constexpr int kL  = 512;

__device__ inline float ldf(const float* p) { return *p; }
__device__ inline float ldf(const bf16* p)  { return __bfloat162float(*p); }
__device__ inline void  stf(float* p, float v) { *p = v; }
__device__ inline void  stf(bf16* p,  float v) { *p = __float2bfloat16(v); }

__device__ inline u32 f2bf2(float a, float b) {
  bf16 ha = __float2bfloat16(a), hb = __float2bfloat16(b);
  unsigned short ua, ub;
  __builtin_memcpy(&ua, &ha, 2);
  __builtin_memcpy(&ub, &hb, 2);
  return (u32)ua | ((u32)ub << 16);
}
__device__ inline unsigned short f2bf(float x) {
  bf16 h = __float2bfloat16(x);
  unsigned short u; __builtin_memcpy(&u, &h, 2);
  return u;
}
__device__ inline short8 frag_ld(const void* p) {   // 16B aligned -> ds/global b128
  short8 r; __builtin_memcpy(&r, p, 16); return r;
}

// ---------------------------------------------------------------------------
// Generic tiled GEMM (scalar VALU; round-1 proven). C = alpha * opA @ opB.
// ---------------------------------------------------------------------------
template<bool TA, bool TB, typename TAe, typename TBe, typename TCe>
__global__ __launch_bounds__(256)
void gemm_kernel(const TAe* __restrict__ A, int lda, long aHi, long aLo,
                 const TBe* __restrict__ Bm, int ldb, long bHi, long bLo,
                 TCe* __restrict__ Cm, int ldc, long cHi, long cLo,
                 int M, int N, int K, float alpha)
{
  const int z = blockIdx.z;
  A  += (long)(z >> 4) * aHi + (long)(z & 15) * aLo;
  Bm += (long)(z >> 4) * bHi + (long)(z & 15) * bLo;
  Cm += (long)(z >> 4) * cHi + (long)(z & 15) * cLo;

  __shared__ __align__(16) float As[16][72];
  __shared__ __align__(16) float Bs[16][72];

  const int tid = threadIdx.x;
  const int tx = tid & 15, ty = tid >> 4;
  const int m0 = blockIdx.x * 64, n0 = blockIdx.y * 64;
  float acc[4][4] = {};

  for (int k0 = 0; k0 < K; k0 += 16) {
    if (TA) {
      for (int l = tid; l < 1024; l += 256) {
        int k = l >> 6, m = l & 63;
        As[k][m] = ldf(&A[(long)(k0 + k) * lda + (m0 + m)]);
      }
    } else {
      for (int l = tid; l < 1024; l += 256) {
        int m = l >> 4, k = l & 15;
        As[k][m] = ldf(&A[(long)(m0 + m) * lda + (k0 + k)]);
      }
    }
    if (TB) {
      for (int l = tid; l < 1024; l += 256) {
        int n = l >> 4, k = l & 15;
        Bs[k][n] = ldf(&Bm[(long)(n0 + n) * ldb + (k0 + k)]);
      }
    } else {
      for (int l = tid; l < 1024; l += 256) {
        int k = l >> 6, n = l & 63;
        Bs[k][n] = ldf(&Bm[(long)(k0 + k) * ldb + (n0 + n)]);
      }
    }
    __syncthreads();
#pragma unroll
    for (int kk = 0; kk < 16; ++kk) {
      float4 av = *(const float4*)&As[kk][ty * 4];
      float4 bv = *(const float4*)&Bs[kk][tx * 4];
      float a[4] = {av.x, av.y, av.z, av.w};
      float b[4] = {bv.x, bv.y, bv.z, bv.w};
#pragma unroll
      for (int i = 0; i < 4; ++i)
#pragma unroll
        for (int j = 0; j < 4; ++j)
          acc[i][j] += a[i] * b[j];
    }
    __syncthreads();
  }
#pragma unroll
  for (int i = 0; i < 4; ++i)
#pragma unroll
    for (int j = 0; j < 4; ++j)
      stf(&Cm[(long)(m0 + ty*4 + i) * ldc + (n0 + tx*4 + j)], alpha * acc[i][j]);
}

// fp32 -> bf16 cast (c_kv internal copy). n multiple of 1024.
__global__ __launch_bounds__(256)
void cast_kernel(const float* __restrict__ src, bf16* __restrict__ dst, int n)
{
  int i = (blockIdx.x * 256 + threadIdx.x) * 4;
  if (i < n) {
    float4 v = *(const float4*)(src + i);
    *(uint2*)((u32*)dst + i / 2) = make_uint2(f2bf2(v.x, v.y), f2bf2(v.z, v.w));
  }
}

// ckv [b][2048][512] -> ckvT [b][512][2048] (bf16). 32x32 LDS tiles.
__global__ __launch_bounds__(256)
void transpose_ckv(const bf16* __restrict__ src, bf16* __restrict__ dst)
{
  __shared__ unsigned short s[32][33];
  const int b = blockIdx.z, t0 = blockIdx.x * 32, l0 = blockIdx.y * 32;
  const int x = threadIdx.x & 31, y = threadIdx.x >> 5;   // y: 0..7
  const unsigned short* sp = (const unsigned short*)(src + (long)b * kT * kL);
  unsigned short* dp = (unsigned short*)(dst + (long)b * kL * kT);
#pragma unroll
  for (int i = 0; i < 4; ++i)
    s[y*4 + i][x] = sp[(long)(t0 + y*4 + i) * kL + l0 + x];
  __syncthreads();
#pragma unroll
  for (int i = 0; i < 4; ++i)
    dp[(long)(l0 + y*4 + i) * kT + t0 + x] = s[x][y*4 + i];
}

// ---------------------------------------------------------------------------
// MFMA flash attention. WG = 256 thr = 4 waves; wave w owns q-block qb=4*wgQ+w
// (16 queries). The WG shares a 32-key Ks LDS tile; PV A-frags stream from
// ckvT (global, L2-resident). mfma_f32_16x16x32_bf16 layouts (m89-verified):
//   A[m=lane&15][k=quad*8+j], B[k=quad*8+j][n=lane&15], D: col=lane&15,
//   row=quad*4+reg. QK: A=Q, B=K rows. PV: O^T = V^T * P^T (A=ckvT rows,
//   B=P rows via per-wave LDS round-trip; wave-local waitcnt, no barriers).
// Softmax in registers (shfl over the 16-lane key axis), base-2 exp
// (log2e folded into k_eff scale), ballot-gated O rescale.
// ---------------------------------------------------------------------------
__global__ __launch_bounds__(256, 2)
void flash_mfma(bf16* __restrict__ qlat, const bf16* __restrict__ ckv,
                const bf16* __restrict__ ckvT)
{
  const int wgQ = blockIdx.x, h = blockIdx.y, b = blockIdx.z;
  const int tid = threadIdx.x;
  const int w = tid >> 6, lane = tid & 63;
  const int quad = lane >> 4, lp = lane & 15;
  const int qb = 4 * wgQ + w, q0 = qb * 16;

  __shared__ __align__(16) bf16 Ks[32][520];              // 33.3 KB, pad->2-way max
  __shared__ __align__(16) unsigned short Pbuf[4][16][40]; // 5 KB, per-wave slices
  unsigned short (*Pw)[40] = Pbuf[w];

  const bf16* ckb = ckv  + (long)b * kT * kL;
  const bf16* ckt = ckvT + (long)b * kL * kT;
  bf16* qbase = qlat + (((long)(b * kNH + h)) * kT + q0) * kL;

  // persistent Q fragments: A[m=lp][k=quad*8+j] per 32-l block
  short8 qf[16];
#pragma unroll
  for (int lb = 0; lb < 16; ++lb)
    qf[lb] = frag_ld(qbase + (long)lp * kL + lb * 32 + quad * 8);

  f4 O[32];
#pragma unroll
  for (int ct = 0; ct < 32; ++ct) O[ct] = f4{0.f, 0.f, 0.f, 0.f};
  float m_r[4] = {-3e38f, -3e38f, -3e38f, -3e38f};
  float l_r[4] = {0.f, 0.f, 0.f, 0.f};

  const int tmax = qb >> 1;
  const int nt = 2 * wgQ + 2;

  for (int t = 0; t < nt; ++t) {
    __syncthreads();
    { // stage Ks[32][512] (padded rows) from ckv rows 32t..32t+31
      const uint4* src = (const uint4*)(ckb + (long)t * 32 * kL);
      for (int i = 0; i < 8; ++i) {
        int idx = tid + 256 * i;               // 2048 uint4 total
        int row = idx >> 6, c = idx & 63;
        *(uint4*)&Ks[row][c * 8] = src[idx];
      }
    }
    __syncthreads();
    if (t > tmax) continue;

    // ---- QK^T: S[16q][32keys], two kb chains ----
    f4 s0 = f4{0.f,0.f,0.f,0.f}, s1 = f4{0.f,0.f,0.f,0.f};
#pragma unroll
    for (int lb = 0; lb < 16; ++lb) {
      short8 b0 = frag_ld(&Ks[lp][lb * 32 + quad * 8]);
      short8 b1 = frag_ld(&Ks[16 + lp][lb * 32 + quad * 8]);
      s0 = __builtin_amdgcn_mfma_f32_16x16x32_bf16(qf[lb], b0, s0, 0, 0, 0);
      s1 = __builtin_amdgcn_mfma_f32_16x16x32_bf16(qf[lb], b1, s1, 0, 0, 0);
    }

    // ---- causal mask on the diagonal tile ----
    if (t == tmax) {
      const int k0 = t * 32;
#pragma unroll
      for (int r = 0; r < 4; ++r) {
        int q = q0 + quad * 4 + r;
        if (k0 + lp > q)      s0[r] = -3e38f;
        if (k0 + 16 + lp > q) s1[r] = -3e38f;
      }
    }

    // ---- online softmax (base-2; scores pre-scaled by log2e/8) ----
    float tm[4], mn[4], al[4], p0[4], p1[4], rs[4];
    bool upd = false;
#pragma unroll
    for (int r = 0; r < 4; ++r) tm[r] = fmaxf(s0[r], s1[r]);
#pragma unroll
    for (int d = 1; d < 16; d <<= 1)
#pragma unroll
      for (int r = 0; r < 4; ++r) tm[r] = fmaxf(tm[r], __shfl_xor(tm[r], d, 64));
#pragma unroll
    for (int r = 0; r < 4; ++r) {
      mn[r] = fmaxf(m_r[r], tm[r]);
      upd = upd || (mn[r] > m_r[r]);
      p0[r] = exp2f(s0[r] - mn[r]);
      p1[r] = exp2f(s1[r] - mn[r]);
      rs[r] = p0[r] + p1[r];
    }
#pragma unroll
    for (int d = 1; d < 16; d <<= 1)
#pragma unroll
      for (int r = 0; r < 4; ++r) rs[r] += __shfl_xor(rs[r], d, 64);
#pragma unroll
    for (int r = 0; r < 4; ++r) {
      al[r] = exp2f(m_r[r] - mn[r]);
      l_r[r] = l_r[r] * al[r] + rs[r];
      m_r[r] = mn[r];
    }

    // ---- P -> per-wave LDS (bf16), then B-frag read ----
#pragma unroll
    for (int r = 0; r < 4; ++r) {
      Pw[quad * 4 + r][lp]      = f2bf(p0[r]);
      Pw[quad * 4 + r][16 + lp] = f2bf(p1[r]);
    }
    asm volatile("s_waitcnt lgkmcnt(0)" ::: "memory");
    short8 pb = frag_ld(&Pw[lp][quad * 8]);   // B[k=quad*8+j][n=lp]

    // ---- ballot-gated O rescale (alpha routed S-domain -> O-domain) ----
    unsigned long long bal = __ballot(upd);
    if (bal) {
      int src = (lp >> 2) << 4;
      float a0 = __shfl(al[0], src, 64), a1 = __shfl(al[1], src, 64);
      float a2 = __shfl(al[2], src, 64), a3 = __shfl(al[3], src, 64);
      int rr = lp & 3;
      float av = rr == 0 ? a0 : rr == 1 ? a1 : rr == 2 ? a2 : a3;
#pragma unroll
      for (int ct = 0; ct < 32; ++ct) {
        O[ct][0] *= av; O[ct][1] *= av; O[ct][2] *= av; O[ct][3] *= av;
      }
    }

    // ---- PV: O^T[c][q] += V^T * P^T, A-frags streamed from ckvT ----
    const bf16* abase = ckt + (long)lp * kT + (long)t * 32 + quad * 8;
    uint4 fb[4];
#pragma unroll
    for (int i = 0; i < 4; ++i) fb[i] = *(const uint4*)(abase + (long)i * 16 * kT);
#pragma unroll
    for (int ct = 0; ct < 32; ++ct) {
      short8 a; __builtin_memcpy(&a, &fb[ct & 3], 16);
      if (ct + 4 < 32) fb[ct & 3] = *(const uint4*)(abase + (long)(ct + 4) * 16 * kT);
      O[ct] = __builtin_amdgcn_mfma_f32_16x16x32_bf16(a, pb, O[ct], 0, 0, 0);
    }
  }

  // ---- epilogue: route 1/l to O-domain, transpose O via LDS, store bf16 ----
  {
    int src = (lp >> 2) << 4;
    float l0 = __shfl(l_r[0], src, 64), l1 = __shfl(l_r[1], src, 64);
    float l2 = __shfl(l_r[2], src, 64), l3 = __shfl(l_r[3], src, 64);
    int rr = lp & 3;
    float lq = rr == 0 ? l0 : rr == 1 ? l1 : rr == 2 ? l2 : l3;
    float inv = 1.0f / lq;

    unsigned short (*cb)[40] = Pbuf[w];
    for (int cc = 0; cc < 16; ++cc) {
#pragma unroll
      for (int i = 0; i < 2; ++i) {
        int ct = cc * 2 + i;
        *(u32*)&cb[lp][i * 16 + quad * 4]     = f2bf2(O[ct][0] * inv, O[ct][1] * inv);
        *(u32*)&cb[lp][i * 16 + quad * 4 + 2] = f2bf2(O[ct][2] * inv, O[ct][3] * inv);
      }
      asm volatile("s_waitcnt lgkmcnt(0)" ::: "memory");
      int qrow = lane >> 2, cl = (lane & 3) * 8;
      uint4 v = *(const uint4*)&cb[qrow][cl];
      *(uint4*)(qbase + (long)qrow * kL + cc * 32 + cl) = v;
      asm volatile("s_waitcnt lgkmcnt(0)" ::: "memory");
    }
  }
}

// ---------------------------------------------------------------------------
extern "C" void kernel_launch(void* const* d_in, const int* in_sizes, int n_in,
                              void* d_out, int out_size, void* d_ws, size_t ws_size,
                              hipStream_t stream)
{
  const float* x     = (const float*)d_in[0];
  const float* W_dq  = (const float*)d_in[1];
  const float* W_uq  = (const float*)d_in[2];
  const float* W_dkv = (const float*)d_in[3];
  const float* W_uk  = (const float*)d_in[4];
  const float* W_uv  = (const float*)d_in[5];
  const float* W_o   = (const float*)d_in[6];

  float* y_out   = (float*)d_out;
  float* ckv_out = y_out + (long)kB * kT * kC;

  // workspace layout (~98.6 MB). ckvT overlaps q_low (dead after qfull gemm).
  char*  ws     = (char*)d_ws;
  float* tmp_qk = (float*)(ws + 0);             // 512x512          1 MB
  float* k_eff  = (float*)(ws + 1048576);       // 1024x512         2 MB
  float* v_eff  = (float*)(ws + 3145728);       // 512x1024         2 MB
  float* q_low  = (float*)(ws + 5242880);       // 4096x512         8 MB
  bf16*  ckvT   = (bf16*)(ws + 5242880);        // [2,512,2048]     4 MB (reuses q_low)
  float* qfull  = (float*)(ws + 13631488);      // 4096x1024       16 MB
  bf16*  ckv_b  = (bf16*)(ws + 30408704);       // [2,2048,512]     4 MB
  bf16*  q_lat  = (bf16*)(ws + 34603008);       // [2,16,2048,512] 64 MB (y_lat in place)

  const dim3 blk(256);
  const long TC = (long)kT * kC, TL = (long)kT * kL;
  const float kScale = 0.125f * 1.44269504088896f;   // 1/sqrt(hs) * log2(e)

  gemm_kernel<true, false, float, float, float><<<dim3(8, 8, 1), blk, 0, stream>>>(
      W_uq, 512, 0, 0, W_uk, 512, 0, 0, tmp_qk, 512, 0, 0, 512, 512, 1024, 1.0f);
  gemm_kernel<true, false, float, float, float><<<dim3(16, 8, 1), blk, 0, stream>>>(
      W_dq, 1024, 0, 0, tmp_qk, 512, 0, 0, k_eff, 512, 0, 0, 1024, 512, 512, kScale);
  gemm_kernel<true, true, float, float, float><<<dim3(8, 16, 1), blk, 0, stream>>>(
      W_uv, 512, 0, 0, W_o, 1024, 0, 0, v_eff, 1024, 0, 0, 512, 1024, 1024, 1.0f);
  gemm_kernel<false, true, float, float, float><<<dim3(64, 8, 1), blk, 0, stream>>>(
      x, 1024, 0, 0, W_dq, 1024, 0, 0, q_low, 512, 0, 0, 4096, 512, 1024, 1.0f);
  gemm_kernel<false, true, float, float, float><<<dim3(64, 16, 1), blk, 0, stream>>>(
      q_low, 512, 0, 0, W_uq, 512, 0, 0, qfull, 1024, 0, 0, 4096, 1024, 512, 1.0f);
  gemm_kernel<false, true, float, float, float><<<dim3(64, 8, 1), blk, 0, stream>>>(
      x, 1024, 0, 0, W_dkv, 1024, 0, 0, ckv_out, 512, 0, 0, 4096, 512, 1024, 1.0f);
  cast_kernel<<<dim3((kB * kT * kL) / 1024), blk, 0, stream>>>(
      ckv_out, ckv_b, kB * kT * kL);
  transpose_ckv<<<dim3(64, 16, 2), blk, 0, stream>>>(ckv_b, ckvT);
  // q_lat = qfull @ k_eff (pre-scaled by log2e/8)
  gemm_kernel<false, false, float, float, bf16><<<dim3(32, 8, 32), blk, 0, stream>>>(
      qfull, 1024, TC, 64,
      k_eff, 512, 0, (long)kHS * kL,
      q_lat, 512, (long)kNH * TL, TL,
      2048, 512, 64, 1.0f);
  flash_mfma<<<dim3(32, 16, 2), blk, 0, stream>>>(q_lat, ckv_b, ckvT);
  gemm_kernel<false, false, bf16, float, float><<<dim3(32, 1, 32), blk, 0, stream>>>(
      q_lat, 512, (long)kNH * TL, TL,
      v_eff, 1024, 0, 64,
      y_out, 1024, TC, 64,
      2048, 64, 512, 1.0f);

  (void)in_sizes; (void)n_in; (void)out_size; (void)ws_size;
}

// Round 4
// 860.460 us; speedup vs baseline: 9.0245x; 2.6927x over previous
//
#include <hip/hip_runtime.h>
#include <hip/hip_bf16.h>

// MLA absorbed causal attention, MI355X round 3:
//  - flash attention: balanced stripe-pair grid (512 WGs, 66 K-rounds each),
//    XOR-swizzled conflict-free Ks, early PV prefetch.
//  - all projections on bf16 MFMA NT GEMM (fp32 accumulate).
// fp32 I/O. d_out = [ y (2*2048*1024) | c_kv (2*2048*512) ] fp32.

using bf16 = __hip_bfloat16;
using u32  = unsigned int;
using short8 = __attribute__((ext_vector_type(8))) short;   // 8 bf16 (4 VGPRs)
using f4     = __attribute__((ext_vector_type(4))) float;   // MFMA accumulator

static constexpr int kB  = 2;
static constexpr int kT  = 2048;
static constexpr int kC  = 1024;
static constexpr int kNH = 16;
static constexpr int kL  = 512;

__device__ inline u32 f2bf2(float a, float b) {
  bf16 ha = __float2bfloat16(a), hb = __float2bfloat16(b);
  unsigned short ua, ub;
  __builtin_memcpy(&ua, &ha, 2);
  __builtin_memcpy(&ub, &hb, 2);
  return (u32)ua | ((u32)ub << 16);
}
__device__ inline unsigned short f2bf(float x) {
  bf16 h = __float2bfloat16(x);
  unsigned short u; __builtin_memcpy(&u, &h, 2);
  return u;
}
__device__ inline short8 frag_ld(const void* p) {   // 16B aligned -> ds/global b128
  short8 r; __builtin_memcpy(&r, p, 16); return r;
}

// fp32 -> bf16 flat cast. n multiple of 1024.
__global__ __launch_bounds__(256)
void cast_kernel(const float* __restrict__ src, bf16* __restrict__ dst, int n)
{
  int i = (blockIdx.x * 256 + threadIdx.x) * 4;
  if (i < n) {
    float4 v = *(const float4*)(src + i);
    *(uint2*)((u32*)dst + i / 2) = make_uint2(f2bf2(v.x, v.y), f2bf2(v.z, v.w));
  }
}

// fp32 [R][C] -> bf16 [C][R] transpose-cast. R,C multiples of 32.
__global__ __launch_bounds__(256)
void tcast_kernel(const float* __restrict__ src, bf16* __restrict__ dst,
                  int R, int C)
{
  __shared__ float s[32][33];
  const int r0 = blockIdx.x * 32, c0 = blockIdx.y * 32;
  const int x = threadIdx.x & 31, y = threadIdx.x >> 5;   // y: 0..7
#pragma unroll
  for (int i = 0; i < 4; ++i)
    s[y*4 + i][x] = src[(long)(r0 + y*4 + i) * C + c0 + x];
  __syncthreads();
  unsigned short* dp = (unsigned short*)dst;
#pragma unroll
  for (int i = 0; i < 4; ++i)
    dp[(long)(c0 + y*4 + i) * R + r0 + x] = f2bf(s[x][y*4 + i]);
}

// ckv [b][2048][512] -> ckvT [b][512][2048] (bf16).
__global__ __launch_bounds__(256)
void transpose_ckv(const bf16* __restrict__ src, bf16* __restrict__ dst)
{
  __shared__ unsigned short s[32][33];
  const int b = blockIdx.z, t0 = blockIdx.x * 32, l0 = blockIdx.y * 32;
  const int x = threadIdx.x & 31, y = threadIdx.x >> 5;
  const unsigned short* sp = (const unsigned short*)(src + (long)b * kT * kL);
  unsigned short* dp = (unsigned short*)(dst + (long)b * kL * kT);
#pragma unroll
  for (int i = 0; i < 4; ++i)
    s[y*4 + i][x] = sp[(long)(t0 + y*4 + i) * kL + l0 + x];
  __syncthreads();
#pragma unroll
  for (int i = 0; i < 4; ++i)
    dp[(long)(l0 + y*4 + i) * kT + t0 + x] = s[x][y*4 + i];
}

// ---------------------------------------------------------------------------
// NT MFMA GEMM: C[m][n] = alpha * sum_k A[m][k] * B[n][k]; A,B bf16 row-major
// over k. Tile 64x64, BK=64, 4 waves; wave w owns m-rows w*16..w*16+15.
// Both A and B fragments are conflict-free ds_read_b128 row segments
// (pad 72: bank group = (lp+quad)%8, 8 lanes each). Batch via blockIdx.z
// decomposed (z>>4, z&15) with (hi,lo) element strides. M,N,K mult of 64.
// ---------------------------------------------------------------------------
template<typename TCe>
__global__ __launch_bounds__(256)
void mm_nt(const bf16* __restrict__ A, int lda, long aHi, long aLo,
           const bf16* __restrict__ Bm, int ldb, long bHi, long bLo,
           TCe* __restrict__ Cm, int ldc, long cHi, long cLo,
           int K, float alpha)
{
  const int z = blockIdx.z;
  A  += (long)(z >> 4) * aHi + (long)(z & 15) * aLo;
  Bm += (long)(z >> 4) * bHi + (long)(z & 15) * bLo;
  Cm += (long)(z >> 4) * cHi + (long)(z & 15) * cLo;

  __shared__ __align__(16) bf16 As[64][72];
  __shared__ __align__(16) bf16 Bs[64][72];

  const int tid = threadIdx.x;
  const int w = tid >> 6, lane = tid & 63;
  const int quad = lane >> 4, lp = lane & 15;
  const int m0 = blockIdx.x * 64, n0 = blockIdx.y * 64;
  const int row = tid >> 2, cseg = (tid & 3) * 16;

  f4 acc[4];
#pragma unroll
  for (int i = 0; i < 4; ++i) acc[i] = f4{0.f, 0.f, 0.f, 0.f};

  for (int k0 = 0; k0 < K; k0 += 64) {
    const bf16* ag = A  + (long)(m0 + row) * lda + k0 + cseg;
    const bf16* bg = Bm + (long)(n0 + row) * ldb + k0 + cseg;
    uint4 a0 = *(const uint4*)ag, a1 = *(const uint4*)(ag + 8);
    uint4 b0 = *(const uint4*)bg, b1 = *(const uint4*)(bg + 8);
    __syncthreads();                       // protect prev-iter frag reads
    *(uint4*)&As[row][cseg] = a0; *(uint4*)&As[row][cseg + 8] = a1;
    *(uint4*)&Bs[row][cseg] = b0; *(uint4*)&Bs[row][cseg + 8] = b1;
    __syncthreads();

    short8 af0 = frag_ld(&As[w*16 + lp][quad * 8]);
    short8 af1 = frag_ld(&As[w*16 + lp][32 + quad * 8]);
#pragma unroll
    for (int nb = 0; nb < 4; ++nb) {
      short8 bf0 = frag_ld(&Bs[nb*16 + lp][quad * 8]);
      short8 bf1 = frag_ld(&Bs[nb*16 + lp][32 + quad * 8]);
      acc[nb] = __builtin_amdgcn_mfma_f32_16x16x32_bf16(af0, bf0, acc[nb], 0, 0, 0);
      acc[nb] = __builtin_amdgcn_mfma_f32_16x16x32_bf16(af1, bf1, acc[nb], 0, 0, 0);
    }
  }
#pragma unroll
  for (int nb = 0; nb < 4; ++nb)
#pragma unroll
    for (int r = 0; r < 4; ++r) {
      float v = alpha * acc[nb][r];
      long off = (long)(m0 + w*16 + quad*4 + r) * ldc + n0 + nb*16 + lp;
      if constexpr (__is_same(TCe, float)) Cm[off] = v;
      else ((unsigned short*)Cm)[off] = f2bf(v);
    }
}

// ---------------------------------------------------------------------------
// MFMA flash attention, balanced. blockIdx.x = j in [0,16): WG processes
// stripe j then stripe 31-j (66 K-rounds total for every WG; 512 WGs = 2/CU).
// Ks[32][512] XOR-swizzled in 16B units (u ^= row&7): staging writes and QK
// B-frag reads both conflict-free. PV A-frags stream from ckvT with early
// issue (covered by softmax); all 4 waves read the same 32KB tile -> L1 hits.
// ---------------------------------------------------------------------------
__global__ __launch_bounds__(256, 2)
void flash_mfma(bf16* __restrict__ qlat, const bf16* __restrict__ ckv,
                const bf16* __restrict__ ckvT)
{
  const int jj = blockIdx.x, h = blockIdx.y, b = blockIdx.z;
  const int tid = threadIdx.x;
  const int w = tid >> 6, lane = tid & 63;
  const int quad = lane >> 4, lp = lane & 15;

  __shared__ __align__(16) bf16 Ks[32 * 512];               // 32 KB swizzled
  __shared__ __align__(16) unsigned short Pbuf[4][16][40];  // 5 KB per-wave
  unsigned short (*Pw)[40] = Pbuf[w];

  const bf16* ckb = ckv  + (long)b * kT * kL;
  const bf16* ckt = ckvT + (long)b * kL * kT;

  for (int half = 0; half < 2; ++half) {
    const int wgQ = half ? (31 - jj) : jj;
    const int qb = 4 * wgQ + w, q0 = qb * 16;
    bf16* qbase = qlat + (((long)(b * kNH + h)) * kT + q0) * kL;

    // persistent Q fragments: A[m=lp][k=quad*8+j] per 32-latent block
    short8 qf[16];
#pragma unroll
    for (int lb = 0; lb < 16; ++lb)
      qf[lb] = frag_ld(qbase + (long)lp * kL + lb * 32 + quad * 8);

    f4 O[32];
#pragma unroll
    for (int ct = 0; ct < 32; ++ct) O[ct] = f4{0.f, 0.f, 0.f, 0.f};
    float m_r[4] = {-3e38f, -3e38f, -3e38f, -3e38f};
    float l_r[4] = {0.f, 0.f, 0.f, 0.f};

    const int tmax = qb >> 1;
    const int nt = 2 * wgQ + 2;

    for (int t = 0; t < nt; ++t) {
      __syncthreads();                      // Ks free (prev compute done)
      { // stage 32 keys, swizzled
        const uint4* src = (const uint4*)(ckb + (long)t * 32 * kL);
#pragma unroll
        for (int i = 0; i < 8; ++i) {
          int idx = tid + 256 * i;
          int r = idx >> 6, u = idx & 63;
          int us = (u & ~7) | ((u ^ r) & 7);
          *(uint4*)&Ks[r * 512 + us * 8] = src[idx];
        }
      }
      __syncthreads();
      if (t > tmax) continue;

      // ---- QK^T: S[16q][32keys] ----
      f4 s0 = f4{0.f,0.f,0.f,0.f}, s1 = f4{0.f,0.f,0.f,0.f};
#pragma unroll
      for (int lb = 0; lb < 16; ++lb) {
        int u = lb * 4 + quad;
        int us8 = ((u & ~7) | ((u ^ lp) & 7)) * 8;
        short8 b0 = frag_ld(&Ks[lp * 512 + us8]);
        short8 b1 = frag_ld(&Ks[(16 + lp) * 512 + us8]);
        s0 = __builtin_amdgcn_mfma_f32_16x16x32_bf16(qf[lb], b0, s0, 0, 0, 0);
        s1 = __builtin_amdgcn_mfma_f32_16x16x32_bf16(qf[lb], b1, s1, 0, 0, 0);
      }

      // ---- early PV A-frag prefetch (independent; latency hidden by softmax)
      const bf16* abase = ckt + (long)lp * kT + t * 32 + quad * 8;
      uint4 fb[4];
#pragma unroll
      for (int i = 0; i < 4; ++i)
        fb[i] = *(const uint4*)(abase + (long)i * 16 * kT);

      // ---- causal mask on the diagonal tile ----
      if (t == tmax) {
        const int k0 = t * 32;
#pragma unroll
        for (int r = 0; r < 4; ++r) {
          int q = q0 + quad * 4 + r;
          if (k0 + lp > q)      s0[r] = -3e38f;
          if (k0 + 16 + lp > q) s1[r] = -3e38f;
        }
      }

      // ---- online softmax (base-2; log2e/8 folded into k_effT) ----
      float tm[4], mn[4], al[4], p0[4], p1[4], rs[4];
      bool upd = false;
#pragma unroll
      for (int r = 0; r < 4; ++r) tm[r] = fmaxf(s0[r], s1[r]);
#pragma unroll
      for (int d = 1; d < 16; d <<= 1)
#pragma unroll
        for (int r = 0; r < 4; ++r) tm[r] = fmaxf(tm[r], __shfl_xor(tm[r], d, 64));
#pragma unroll
      for (int r = 0; r < 4; ++r) {
        mn[r] = fmaxf(m_r[r], tm[r]);
        upd = upd || (mn[r] > m_r[r]);
        p0[r] = exp2f(s0[r] - mn[r]);
        p1[r] = exp2f(s1[r] - mn[r]);
        rs[r] = p0[r] + p1[r];
      }
#pragma unroll
      for (int d = 1; d < 16; d <<= 1)
#pragma unroll
        for (int r = 0; r < 4; ++r) rs[r] += __shfl_xor(rs[r], d, 64);
#pragma unroll
      for (int r = 0; r < 4; ++r) {
        al[r] = exp2f(m_r[r] - mn[r]);
        l_r[r] = l_r[r] * al[r] + rs[r];
        m_r[r] = mn[r];
      }

      // ---- P -> per-wave LDS (bf16), read back as B-frag ----
#pragma unroll
      for (int r = 0; r < 4; ++r) {
        Pw[quad * 4 + r][lp]      = f2bf(p0[r]);
        Pw[quad * 4 + r][16 + lp] = f2bf(p1[r]);
      }
      asm volatile("s_waitcnt lgkmcnt(0)" ::: "memory");
      short8 pb = frag_ld(&Pw[lp][quad * 8]);   // B[k=quad*8+j][n=lp]

      // ---- ballot-gated O rescale (alpha S-domain -> O-domain) ----
      unsigned long long bal = __ballot(upd);
      if (bal) {
        int src = (lp >> 2) << 4;
        float a0 = __shfl(al[0], src, 64), a1 = __shfl(al[1], src, 64);
        float a2 = __shfl(al[2], src, 64), a3 = __shfl(al[3], src, 64);
        int rr = lp & 3;
        float av = rr == 0 ? a0 : rr == 1 ? a1 : rr == 2 ? a2 : a3;
#pragma unroll
        for (int ct = 0; ct < 32; ++ct) {
          O[ct][0] *= av; O[ct][1] *= av; O[ct][2] *= av; O[ct][3] *= av;
        }
      }

      // ---- PV: O^T[c][q] += V^T * P^T ----
#pragma unroll
      for (int ct = 0; ct < 32; ++ct) {
        short8 a; __builtin_memcpy(&a, &fb[ct & 3], 16);
        if (ct + 4 < 32) fb[ct & 3] = *(const uint4*)(abase + (long)(ct + 4) * 16 * kT);
        O[ct] = __builtin_amdgcn_mfma_f32_16x16x32_bf16(a, pb, O[ct], 0, 0, 0);
      }
    }

    // ---- epilogue: 1/l to O-domain, transpose O via LDS slice, store bf16 ----
    {
      int src = (lp >> 2) << 4;
      float l0 = __shfl(l_r[0], src, 64), l1 = __shfl(l_r[1], src, 64);
      float l2 = __shfl(l_r[2], src, 64), l3 = __shfl(l_r[3], src, 64);
      int rr = lp & 3;
      float lq = rr == 0 ? l0 : rr == 1 ? l1 : rr == 2 ? l2 : l3;
      float inv = 1.0f / lq;

      unsigned short (*cb)[40] = Pbuf[w];
      for (int cc = 0; cc < 16; ++cc) {
#pragma unroll
        for (int i = 0; i < 2; ++i) {
          int ct = cc * 2 + i;
          *(u32*)&cb[lp][i * 16 + quad * 4]     = f2bf2(O[ct][0] * inv, O[ct][1] * inv);
          *(u32*)&cb[lp][i * 16 + quad * 4 + 2] = f2bf2(O[ct][2] * inv, O[ct][3] * inv);
        }
        asm volatile("s_waitcnt lgkmcnt(0)" ::: "memory");
        int qrow = lane >> 2, cl = (lane & 3) * 8;
        uint4 v = *(const uint4*)&cb[qrow][cl];
        *(uint4*)(qbase + (long)qrow * kL + cc * 32 + cl) = v;
        asm volatile("s_waitcnt lgkmcnt(0)" ::: "memory");
      }
    }
  }
}

// ---------------------------------------------------------------------------
extern "C" void kernel_launch(void* const* d_in, const int* in_sizes, int n_in,
                              void* d_out, int out_size, void* d_ws, size_t ws_size,
                              hipStream_t stream)
{
  const float* x     = (const float*)d_in[0];
  const float* W_dq  = (const float*)d_in[1];
  const float* W_uq  = (const float*)d_in[2];
  const float* W_dkv = (const float*)d_in[3];
  const float* W_uk  = (const float*)d_in[4];
  const float* W_uv  = (const float*)d_in[5];
  const float* W_o   = (const float*)d_in[6];

  float* y_out   = (float*)d_out;
  float* ckv_out = y_out + (long)kB * kT * kC;

  // workspace layout, max offset 101,711,872 B (== round-1/2 proven bound)
  char* ws = (char*)d_ws;
  bf16* q_lat  = (bf16*)(ws + 0);            // 64 MB  (y_lat in place)
  bf16* ckv_b  = (bf16*)(ws + 67108864);     //  4 MB
  bf16* ckvT   = (bf16*)(ws + 71303168);     //  4 MB
  bf16* xb     = (bf16*)(ws + 75497472);     //  8 MB
  bf16* q_lowb = (bf16*)(ws + 83886080);     //  4 MB
  bf16* qfullb = (bf16*)(ws + 88080384);     //  8 MB (scratch overlap below)
  bf16* W_uqTb = (bf16*)(ws + 88080384);     //  1 MB  [dead before qfullb write]
  bf16* W_ukTb = (bf16*)(ws + 89128960);     //  1 MB
  bf16* W_uvTb = (bf16*)(ws + 90177536);     //  1 MB
  bf16* W_dqTb = (bf16*)(ws + 91226112);     //  1 MB
  bf16* W_ob   = (bf16*)(ws + 92274688);     //  2 MB
  bf16* tmpT   = (bf16*)(ws + 94371840);     // 0.5 MB
  bf16* k_effT = (bf16*)(ws + 96468992);     //  1 MB  [512 l][1024 c]
  bf16* v_effT = (bf16*)(ws + 97517568);     //  1 MB  [1024 j][512 l]
  bf16* W_dqb  = (bf16*)(ws + 98566144);     //  1 MB
  bf16* W_uqb  = (bf16*)(ws + 99614720);     //  1 MB
  bf16* W_dkvb = (bf16*)(ws + 100663296);    //  1 MB

  const dim3 blk(256);
  const long TC = (long)kT * kC, TL = (long)kT * kL;
  const float kScale = 0.125f * 1.44269504088896f;   // 1/sqrt(hs) * log2(e)

  // casts
  cast_kernel<<<dim3(4096), blk, 0, stream>>>(x,     xb,     4194304);
  cast_kernel<<<dim3(512),  blk, 0, stream>>>(W_dq,  W_dqb,  524288);
  cast_kernel<<<dim3(512),  blk, 0, stream>>>(W_uq,  W_uqb,  524288);
  cast_kernel<<<dim3(512),  blk, 0, stream>>>(W_dkv, W_dkvb, 524288);
  cast_kernel<<<dim3(1024), blk, 0, stream>>>(W_o,   W_ob,   1048576);
  // transpose-casts
  tcast_kernel<<<dim3(32, 16), blk, 0, stream>>>(W_uq, W_uqTb, 1024, 512);
  tcast_kernel<<<dim3(32, 16), blk, 0, stream>>>(W_uk, W_ukTb, 1024, 512);
  tcast_kernel<<<dim3(32, 16), blk, 0, stream>>>(W_uv, W_uvTb, 1024, 512);
  tcast_kernel<<<dim3(16, 32), blk, 0, stream>>>(W_dq, W_dqTb, 512, 1024);

  // tmpT[l,q] = sum_c W_uk[c,l] * W_uq[c,q]
  mm_nt<bf16><<<dim3(8, 8, 1), blk, 0, stream>>>(
      W_ukTb, 1024, 0, 0, W_uqTb, 1024, 0, 0, tmpT, 512, 0, 0, 1024, 1.0f);
  // k_effT[l,c] = sum_q tmpT[l,q] * W_dq[q,c]   (scaled by log2e/8)
  mm_nt<bf16><<<dim3(8, 16, 1), blk, 0, stream>>>(
      tmpT, 512, 0, 0, W_dqTb, 512, 0, 0, k_effT, 1024, 0, 0, 512, kScale);
  // v_effT[j,l] = sum_c W_o[j,c] * W_uv[c,l]
  mm_nt<bf16><<<dim3(16, 8, 1), blk, 0, stream>>>(
      W_ob, 1024, 0, 0, W_uvTb, 1024, 0, 0, v_effT, 512, 0, 0, 1024, 1.0f);
  // q_low = x @ W_dq^T
  mm_nt<bf16><<<dim3(64, 8, 1), blk, 0, stream>>>(
      xb, 1024, 0, 0, W_dqb, 1024, 0, 0, q_lowb, 512, 0, 0, 1024, 1.0f);
  // qfull = q_low @ W_uq^T
  mm_nt<bf16><<<dim3(64, 16, 1), blk, 0, stream>>>(
      q_lowb, 512, 0, 0, W_uqb, 512, 0, 0, qfullb, 1024, 0, 0, 512, 1.0f);
  // c_kv = x @ W_dkv^T  -> fp32 d_out tail
  mm_nt<float><<<dim3(64, 8, 1), blk, 0, stream>>>(
      xb, 1024, 0, 0, W_dkvb, 1024, 0, 0, ckv_out, 512, 0, 0, 1024, 1.0f);
  cast_kernel<<<dim3(2048), blk, 0, stream>>>(ckv_out, ckv_b, 2097152);
  transpose_ckv<<<dim3(64, 16, 2), blk, 0, stream>>>(ckv_b, ckvT);
  // q_lat[b,h] = qfull[b,:,h*64:+64] @ k_effT[:,h*64:+64]^T
  mm_nt<bf16><<<dim3(32, 8, 32), blk, 0, stream>>>(
      qfullb, 1024, TC, 64,
      k_effT, 1024, 0, 64,
      q_lat, 512, (long)kNH * TL, TL,
      64, 1.0f);
  flash_mfma<<<dim3(16, 16, 2), blk, 0, stream>>>(q_lat, ckv_b, ckvT);
  // y[b,:,h*64:+64] = y_lat[b,h] @ v_effT[h*64:+64,:]^T
  mm_nt<float><<<dim3(32, 1, 32), blk, 0, stream>>>(
      q_lat, 512, (long)kNH * TL, TL,
      v_effT, 512, 0, (long)64 * 512,
      y_out, 1024, TC, 64,
      512, 1.0f);

  (void)in_sizes; (void)n_in; (void)out_size; (void)ws_size;
}

// Round 6
// 801.717 us; speedup vs baseline: 9.6857x; 1.0733x over previous
//
#include <hip/hip_runtime.h>
#include <hip/hip_bf16.h>

// MLA absorbed causal attention, MI355X round 5:
//  same compute as round 4 (flash v3: S^T = K*Q^T, LDS-staged KsT, pipelined
//  staging), but d_out is written ONLY at launch end: c_kv GEMM -> bf16 ckv_b,
//  final upcast kernel writes the fp32 c_kv output tail last (fixes the
//  post-timing output-1 divergence: no early-write window on d_out).
// fp32 I/O. d_out = [ y (2*2048*1024) | c_kv (2*2048*512) ] fp32.

using bf16 = __hip_bfloat16;
using u32  = unsigned int;
using short8 = __attribute__((ext_vector_type(8))) short;   // 8 bf16 (4 VGPRs)
using f4     = __attribute__((ext_vector_type(4))) float;   // MFMA accumulator

static constexpr int kB  = 2;
static constexpr int kT  = 2048;
static constexpr int kC  = 1024;
static constexpr int kNH = 16;
static constexpr int kL  = 512;

__device__ inline u32 f2bf2(float a, float b) {
  bf16 ha = __float2bfloat16(a), hb = __float2bfloat16(b);
  unsigned short ua, ub;
  __builtin_memcpy(&ua, &ha, 2);
  __builtin_memcpy(&ub, &hb, 2);
  return (u32)ua | ((u32)ub << 16);
}
__device__ inline unsigned short f2bf(float x) {
  bf16 h = __float2bfloat16(x);
  unsigned short u; __builtin_memcpy(&u, &h, 2);
  return u;
}
__device__ inline short8 frag_ld(const void* p) {   // 16B aligned -> ds/global b128
  short8 r; __builtin_memcpy(&r, p, 16); return r;
}

// fp32 -> bf16 flat cast. n multiple of 1024.
__global__ __launch_bounds__(256)
void cast_kernel(const float* __restrict__ src, bf16* __restrict__ dst, int n)
{
  int i = (blockIdx.x * 256 + threadIdx.x) * 4;
  if (i < n) {
    float4 v = *(const float4*)(src + i);
    *(uint2*)((u32*)dst + i / 2) = make_uint2(f2bf2(v.x, v.y), f2bf2(v.z, v.w));
  }
}

// bf16 -> fp32 upcast (final c_kv output write). n multiple of 1024.
__global__ __launch_bounds__(256)
void upcast_kernel(const bf16* __restrict__ src, float* __restrict__ dst, int n)
{
  int i = (blockIdx.x * 256 + threadIdx.x) * 4;
  if (i < n) {
    uint2 v = *(const uint2*)((const u32*)src + i / 2);
    float4 o;
    o.x = __uint_as_float(v.x << 16);
    o.y = __uint_as_float(v.x & 0xffff0000u);
    o.z = __uint_as_float(v.y << 16);
    o.w = __uint_as_float(v.y & 0xffff0000u);
    *(float4*)(dst + i) = o;
  }
}

// fp32 [R][C] -> bf16 [C][R] transpose-cast. R,C multiples of 32.
__global__ __launch_bounds__(256)
void tcast_kernel(const float* __restrict__ src, bf16* __restrict__ dst,
                  int R, int C)
{
  __shared__ float s[32][33];
  const int r0 = blockIdx.x * 32, c0 = blockIdx.y * 32;
  const int x = threadIdx.x & 31, y = threadIdx.x >> 5;   // y: 0..7
#pragma unroll
  for (int i = 0; i < 4; ++i)
    s[y*4 + i][x] = src[(long)(r0 + y*4 + i) * C + c0 + x];
  __syncthreads();
  unsigned short* dp = (unsigned short*)dst;
#pragma unroll
  for (int i = 0; i < 4; ++i)
    dp[(long)(c0 + y*4 + i) * R + r0 + x] = f2bf(s[x][y*4 + i]);
}

// ckv [b][2048][512] -> ckvT [b][512][2048] (bf16).
__global__ __launch_bounds__(256)
void transpose_ckv(const bf16* __restrict__ src, bf16* __restrict__ dst)
{
  __shared__ unsigned short s[32][33];
  const int b = blockIdx.z, t0 = blockIdx.x * 32, l0 = blockIdx.y * 32;
  const int x = threadIdx.x & 31, y = threadIdx.x >> 5;
  const unsigned short* sp = (const unsigned short*)(src + (long)b * kT * kL);
  unsigned short* dp = (unsigned short*)(dst + (long)b * kL * kT);
#pragma unroll
  for (int i = 0; i < 4; ++i)
    s[y*4 + i][x] = sp[(long)(t0 + y*4 + i) * kL + l0 + x];
  __syncthreads();
#pragma unroll
  for (int i = 0; i < 4; ++i)
    dp[(long)(l0 + y*4 + i) * kT + t0 + x] = s[x][y*4 + i];
}

// ---------------------------------------------------------------------------
// NT MFMA GEMM (round-3 proven): C[m][n] = alpha * sum_k A[m][k] * B[n][k].
// ---------------------------------------------------------------------------
template<typename TCe>
__global__ __launch_bounds__(256)
void mm_nt(const bf16* __restrict__ A, int lda, long aHi, long aLo,
           const bf16* __restrict__ Bm, int ldb, long bHi, long bLo,
           TCe* __restrict__ Cm, int ldc, long cHi, long cLo,
           int K, float alpha)
{
  const int z = blockIdx.z;
  A  += (long)(z >> 4) * aHi + (long)(z & 15) * aLo;
  Bm += (long)(z >> 4) * bHi + (long)(z & 15) * bLo;
  Cm += (long)(z >> 4) * cHi + (long)(z & 15) * cLo;

  __shared__ __align__(16) bf16 As[64][72];
  __shared__ __align__(16) bf16 Bs[64][72];

  const int tid = threadIdx.x;
  const int w = tid >> 6, lane = tid & 63;
  const int quad = lane >> 4, lp = lane & 15;
  const int m0 = blockIdx.x * 64, n0 = blockIdx.y * 64;
  const int row = tid >> 2, cseg = (tid & 3) * 16;

  f4 acc[4];
#pragma unroll
  for (int i = 0; i < 4; ++i) acc[i] = f4{0.f, 0.f, 0.f, 0.f};

  for (int k0 = 0; k0 < K; k0 += 64) {
    const bf16* ag = A  + (long)(m0 + row) * lda + k0 + cseg;
    const bf16* bg = Bm + (long)(n0 + row) * ldb + k0 + cseg;
    uint4 a0 = *(const uint4*)ag, a1 = *(const uint4*)(ag + 8);
    uint4 b0 = *(const uint4*)bg, b1 = *(const uint4*)(bg + 8);
    __syncthreads();
    *(uint4*)&As[row][cseg] = a0; *(uint4*)&As[row][cseg + 8] = a1;
    *(uint4*)&Bs[row][cseg] = b0; *(uint4*)&Bs[row][cseg + 8] = b1;
    __syncthreads();

    short8 af0 = frag_ld(&As[w*16 + lp][quad * 8]);
    short8 af1 = frag_ld(&As[w*16 + lp][32 + quad * 8]);
#pragma unroll
    for (int nb = 0; nb < 4; ++nb) {
      short8 bf0 = frag_ld(&Bs[nb*16 + lp][quad * 8]);
      short8 bf1 = frag_ld(&Bs[nb*16 + lp][32 + quad * 8]);
      acc[nb] = __builtin_amdgcn_mfma_f32_16x16x32_bf16(af0, bf0, acc[nb], 0, 0, 0);
      acc[nb] = __builtin_amdgcn_mfma_f32_16x16x32_bf16(af1, bf1, acc[nb], 0, 0, 0);
    }
  }
#pragma unroll
  for (int nb = 0; nb < 4; ++nb)
#pragma unroll
    for (int r = 0; r < 4; ++r) {
      float v = alpha * acc[nb][r];
      long off = (long)(m0 + w*16 + quad*4 + r) * ldc + n0 + nb*16 + lp;
      if constexpr (__is_same(TCe, float)) Cm[off] = v;
      else ((unsigned short*)Cm)[off] = f2bf(v);
    }
}

// ---------------------------------------------------------------------------
// MFMA flash attention v3 (round-4 compute, correctness-verified first-launch).
// ---------------------------------------------------------------------------
__global__ __launch_bounds__(256, 2)
void flash_mfma(bf16* __restrict__ qlat, const bf16* __restrict__ ckv,
                const bf16* __restrict__ ckvT)
{
  const int jj = blockIdx.x, h = blockIdx.y, b = blockIdx.z;
  const int tid = threadIdx.x;
  const int w = tid >> 6, lane = tid & 63;
  const int quad = lane >> 4, lp = lane & 15;

  __shared__ __align__(16) bf16 Ks[32 * 512];              // 32 KB, swizzled
  __shared__ __align__(16) bf16 KsT[512][40];              // 40 KB, padded rows
  __shared__ __align__(16) unsigned short Pbuf[4][16][40]; // 5 KB per-wave

  unsigned short (*Pw)[40] = Pbuf[w];
  u32* eb = (u32*)&Pbuf[w][0][0];                          // epilogue alias [16][20]

  const bf16*  ckb  = ckv  + (long)b * kT * kL;
  const uint4* ckb4 = (const uint4*)ckb;
  const bf16*  ckt  = ckvT + (long)b * kL * kT;

  for (int half = 0; half < 2; ++half) {
    const int wgQ = half ? (31 - jj) : jj;
    const int qb = 4 * wgQ + w, q0 = qb * 16;
    bf16* qbase = qlat + (((long)(b * kNH + h)) * kT + q0) * kL;

    // persistent Q fragments (B-operand form): Q[q=lp][lb*32 + quad*8 + j]
    short8 qf[16];
#pragma unroll
    for (int lb = 0; lb < 16; ++lb)
      qf[lb] = frag_ld(qbase + (long)lp * kL + lb * 32 + quad * 8);

    f4 O[32];
#pragma unroll
    for (int ct = 0; ct < 32; ++ct) O[ct] = f4{0.f, 0.f, 0.f, 0.f};
    float m_r = -3e38f, l_r = 0.f;

    const int tmax = qb >> 1;
    const int nt = 2 * wgQ + 2;

    for (int t = 0; t < nt; ++t) {
      // scattered KsT source loads issued BEFORE the barrier
      uint4 kt[8];
#pragma unroll
      for (int i = 0; i < 8; ++i) {
        int idx = tid + 256 * i;
        kt[i] = *(const uint4*)(ckt + (long)(idx >> 2) * kT + t * 32 + (idx & 3) * 8);
      }
      __syncthreads();                       // prev round's compute done
#pragma unroll
      for (int i = 0; i < 8; ++i) {
        int idx = tid + 256 * i;
        *(uint4*)&KsT[idx >> 2][(idx & 3) * 8] = kt[i];
      }
      uint4 ka[8];
#pragma unroll
      for (int i = 0; i < 8; ++i) ka[i] = ckb4[(long)t * 2048 + tid + 256 * i];
#pragma unroll
      for (int i = 0; i < 8; ++i) {
        int idx = tid + 256 * i;
        int r = idx >> 6, u = idx & 63;
        int us = (u & ~7) | ((u ^ r) & 7);
        *(uint4*)&Ks[r * 512 + us * 8] = ka[i];
      }
      __syncthreads();                       // tiles ready
      if (t > tmax) continue;

      // ---- S^T = K * Q^T : two 16-key m-tiles ----
      f4 s0 = f4{0.f,0.f,0.f,0.f}, s1 = f4{0.f,0.f,0.f,0.f};
#pragma unroll
      for (int lb = 0; lb < 16; ++lb) {
        int u = lb * 4 + quad;
        int us8 = ((u & ~7) | ((u ^ lp) & 7)) * 8;
        short8 a0 = frag_ld(&Ks[lp * 512 + us8]);
        short8 a1 = frag_ld(&Ks[(16 + lp) * 512 + us8]);
        s0 = __builtin_amdgcn_mfma_f32_16x16x32_bf16(a0, qf[lb], s0, 0, 0, 0);
        s1 = __builtin_amdgcn_mfma_f32_16x16x32_bf16(a1, qf[lb], s1, 0, 0, 0);
      }

      // ---- causal mask ----
      if (t == tmax) {
        const int k0 = t * 32, q = q0 + lp;
#pragma unroll
        for (int r = 0; r < 4; ++r) {
          if (k0 + quad * 4 + r > q)      s0[r] = -3e38f;
          if (k0 + 16 + quad * 4 + r > q) s1[r] = -3e38f;
        }
      }

      // ---- online softmax (lane-local q; 2 shfl levels) ----
      float mold = m_r;
      float tm = fmaxf(fmaxf(fmaxf(s0[0], s0[1]), fmaxf(s0[2], s0[3])),
                       fmaxf(fmaxf(s1[0], s1[1]), fmaxf(s1[2], s1[3])));
      tm = fmaxf(tm, __shfl_xor(tm, 16, 64));
      tm = fmaxf(tm, __shfl_xor(tm, 32, 64));
      float mn = fmaxf(mold, tm);
      bool upd = mn > mold;
      float al = exp2f(mold - mn);
      float p0[4], p1[4], rs = 0.f;
#pragma unroll
      for (int r = 0; r < 4; ++r) {
        p0[r] = exp2f(s0[r] - mn);
        p1[r] = exp2f(s1[r] - mn);
        rs += p0[r] + p1[r];
      }
      rs += __shfl_xor(rs, 16, 64);
      rs += __shfl_xor(rs, 32, 64);
      l_r = l_r * al + rs;
      m_r = mn;

      // ---- P^T -> per-wave LDS [q=lp][key], read back as B-frag ----
      *(uint2*)&Pw[lp][quad * 4] =
          make_uint2(f2bf2(p0[0], p0[1]), f2bf2(p0[2], p0[3]));
      *(uint2*)&Pw[lp][16 + quad * 4] =
          make_uint2(f2bf2(p1[0], p1[1]), f2bf2(p1[2], p1[3]));
      asm volatile("s_waitcnt lgkmcnt(0)" ::: "memory");
      short8 pb = frag_ld(&Pw[lp][quad * 8]);

      // ---- rescale O^T (lane-local alpha) ----
      if (__ballot(upd)) {
#pragma unroll
        for (int ct = 0; ct < 32; ++ct) {
          O[ct][0] *= al; O[ct][1] *= al; O[ct][2] *= al; O[ct][3] *= al;
        }
      }

      // ---- PV: O^T[lat][q] += V^T * P^T, A-frags row-read from KsT ----
#pragma unroll
      for (int ct = 0; ct < 32; ++ct) {
        short8 a = frag_ld(&KsT[ct * 16 + lp][quad * 8]);
        O[ct] = __builtin_amdgcn_mfma_f32_16x16x32_bf16(a, pb, O[ct], 0, 0, 0);
      }
    }

    // ---- epilogue ----
    {
      float inv = 1.0f / l_r;
      for (int cc = 0; cc < 16; ++cc) {
#pragma unroll
        for (int i = 0; i < 2; ++i) {
          int ct = cc * 2 + i;
          *(uint2*)&eb[lp * 20 + i * 8 + quad * 2] =
              make_uint2(f2bf2(O[ct][0] * inv, O[ct][1] * inv),
                         f2bf2(O[ct][2] * inv, O[ct][3] * inv));
        }
        asm volatile("s_waitcnt lgkmcnt(0)" ::: "memory");
        int qrow = lane >> 2, seg = lane & 3;
        uint4 v = *(const uint4*)&eb[qrow * 20 + seg * 4];
        *(uint4*)(qbase + (long)qrow * kL + cc * 32 + seg * 8) = v;
        asm volatile("s_waitcnt lgkmcnt(0)" ::: "memory");
      }
    }
  }
}

// ---------------------------------------------------------------------------
extern "C" void kernel_launch(void* const* d_in, const int* in_sizes, int n_in,
                              void* d_out, int out_size, void* d_ws, size_t ws_size,
                              hipStream_t stream)
{
  const float* x     = (const float*)d_in[0];
  const float* W_dq  = (const float*)d_in[1];
  const float* W_uq  = (const float*)d_in[2];
  const float* W_dkv = (const float*)d_in[3];
  const float* W_uk  = (const float*)d_in[4];
  const float* W_uv  = (const float*)d_in[5];
  const float* W_o   = (const float*)d_in[6];

  float* y_out   = (float*)d_out;
  float* ckv_out = y_out + (long)kB * kT * kC;

  // workspace layout (max 101,711,872 B, proven bound)
  char* ws = (char*)d_ws;
  bf16* q_lat  = (bf16*)(ws + 0);            // 64 MB  (y_lat in place)
  bf16* ckv_b  = (bf16*)(ws + 67108864);     //  4 MB
  bf16* ckvT   = (bf16*)(ws + 71303168);     //  4 MB
  bf16* xb     = (bf16*)(ws + 75497472);     //  8 MB
  bf16* q_lowb = (bf16*)(ws + 83886080);     //  4 MB
  bf16* qfullb = (bf16*)(ws + 88080384);     //  8 MB (scratch overlap below)
  bf16* W_uqTb = (bf16*)(ws + 88080384);     //  1 MB  [dead before qfullb write]
  bf16* W_ukTb = (bf16*)(ws + 89128960);     //  1 MB
  bf16* W_uvTb = (bf16*)(ws + 90177536);     //  1 MB
  bf16* W_dqTb = (bf16*)(ws + 91226112);     //  1 MB
  bf16* W_ob   = (bf16*)(ws + 92274688);     //  2 MB
  bf16* tmpT   = (bf16*)(ws + 94371840);     // 0.5 MB
  bf16* k_effT = (bf16*)(ws + 96468992);     //  1 MB  [512 l][1024 c]
  bf16* v_effT = (bf16*)(ws + 97517568);     //  1 MB  [1024 j][512 l]
  bf16* W_dqb  = (bf16*)(ws + 98566144);     //  1 MB
  bf16* W_uqb  = (bf16*)(ws + 99614720);     //  1 MB
  bf16* W_dkvb = (bf16*)(ws + 100663296);    //  1 MB

  const dim3 blk(256);
  const long TC = (long)kT * kC, TL = (long)kT * kL;
  const float kScale = 0.125f * 1.44269504088896f;   // 1/sqrt(hs) * log2(e)

  cast_kernel<<<dim3(4096), blk, 0, stream>>>(x,     xb,     4194304);
  cast_kernel<<<dim3(512),  blk, 0, stream>>>(W_dq,  W_dqb,  524288);
  cast_kernel<<<dim3(512),  blk, 0, stream>>>(W_uq,  W_uqb,  524288);
  cast_kernel<<<dim3(512),  blk, 0, stream>>>(W_dkv, W_dkvb, 524288);
  cast_kernel<<<dim3(1024), blk, 0, stream>>>(W_o,   W_ob,   1048576);
  tcast_kernel<<<dim3(32, 16), blk, 0, stream>>>(W_uq, W_uqTb, 1024, 512);
  tcast_kernel<<<dim3(32, 16), blk, 0, stream>>>(W_uk, W_ukTb, 1024, 512);
  tcast_kernel<<<dim3(32, 16), blk, 0, stream>>>(W_uv, W_uvTb, 1024, 512);
  tcast_kernel<<<dim3(16, 32), blk, 0, stream>>>(W_dq, W_dqTb, 512, 1024);

  mm_nt<bf16><<<dim3(8, 8, 1), blk, 0, stream>>>(
      W_ukTb, 1024, 0, 0, W_uqTb, 1024, 0, 0, tmpT, 512, 0, 0, 1024, 1.0f);
  mm_nt<bf16><<<dim3(8, 16, 1), blk, 0, stream>>>(
      tmpT, 512, 0, 0, W_dqTb, 512, 0, 0, k_effT, 1024, 0, 0, 512, kScale);
  mm_nt<bf16><<<dim3(16, 8, 1), blk, 0, stream>>>(
      W_ob, 1024, 0, 0, W_uvTb, 1024, 0, 0, v_effT, 512, 0, 0, 1024, 1.0f);
  mm_nt<bf16><<<dim3(64, 8, 1), blk, 0, stream>>>(
      xb, 1024, 0, 0, W_dqb, 1024, 0, 0, q_lowb, 512, 0, 0, 1024, 1.0f);
  mm_nt<bf16><<<dim3(64, 16, 1), blk, 0, stream>>>(
      q_lowb, 512, 0, 0, W_uqb, 512, 0, 0, qfullb, 1024, 0, 0, 512, 1.0f);
  // c_kv -> bf16 ckv_b directly (no early d_out write)
  mm_nt<bf16><<<dim3(64, 8, 1), blk, 0, stream>>>(
      xb, 1024, 0, 0, W_dkvb, 1024, 0, 0, ckv_b, 512, 0, 0, 1024, 1.0f);
  transpose_ckv<<<dim3(64, 16, 2), blk, 0, stream>>>(ckv_b, ckvT);
  mm_nt<bf16><<<dim3(32, 8, 32), blk, 0, stream>>>(
      qfullb, 1024, TC, 64,
      k_effT, 1024, 0, 64,
      q_lat, 512, (long)kNH * TL, TL,
      64, 1.0f);
  flash_mfma<<<dim3(16, 16, 2), blk, 0, stream>>>(q_lat, ckv_b, ckvT);
  mm_nt<float><<<dim3(32, 1, 32), blk, 0, stream>>>(
      q_lat, 512, (long)kNH * TL, TL,
      v_effT, 512, 0, (long)64 * 512,
      y_out, 1024, TC, 64,
      512, 1.0f);
  // FINAL kernel: write the fp32 c_kv output tail last.
  upcast_kernel<<<dim3(2048), blk, 0, stream>>>(ckv_b, ckv_out, 2097152);

  (void)in_sizes; (void)n_in; (void)out_size; (void)ws_size;
}

// Round 7
// 465.021 us; speedup vs baseline: 16.6986x; 1.7240x over previous
//
#include <hip/hip_runtime.h>
#include <hip/hip_bf16.h>

// MLA absorbed causal attention, MI355X round 6:
//  flash v4: staging via __builtin_amdgcn_global_load_lds (zero staging VGPRs
//  -> no scratch spill; R5 showed 836 MB phantom HBM writes = spill traffic).
//  Swizzles applied via per-lane GLOBAL source permutation (LDS dest is
//  wave-uniform base + lane*16). Ks: 16B-block xor (QK reads 2-way max).
//  KsT[512][32]: seg ^ ((row>>1)&3) (PV reads exactly 2-way = free).
// fp32 I/O. d_out = [ y (2*2048*1024) | c_kv (2*2048*512) ] fp32.

using bf16 = __hip_bfloat16;
using u32  = unsigned int;
using short8 = __attribute__((ext_vector_type(8))) short;   // 8 bf16 (4 VGPRs)
using f4     = __attribute__((ext_vector_type(4))) float;   // MFMA accumulator

static constexpr int kB  = 2;
static constexpr int kT  = 2048;
static constexpr int kC  = 1024;
static constexpr int kNH = 16;
static constexpr int kL  = 512;

__device__ inline u32 f2bf2(float a, float b) {
  bf16 ha = __float2bfloat16(a), hb = __float2bfloat16(b);
  unsigned short ua, ub;
  __builtin_memcpy(&ua, &ha, 2);
  __builtin_memcpy(&ub, &hb, 2);
  return (u32)ua | ((u32)ub << 16);
}
__device__ inline unsigned short f2bf(float x) {
  bf16 h = __float2bfloat16(x);
  unsigned short u; __builtin_memcpy(&u, &h, 2);
  return u;
}
__device__ inline short8 frag_ld(const void* p) {   // 16B aligned -> ds/global b128
  short8 r; __builtin_memcpy(&r, p, 16); return r;
}
// async global->LDS DMA, 16 B/lane. lds base wave-uniform; dest = base + lane*16.
__device__ inline void g2lds16(const bf16* g, bf16* l) {
  __builtin_amdgcn_global_load_lds(
      (const __attribute__((address_space(1))) u32*)g,
      (__attribute__((address_space(3))) u32*)l, 16, 0, 0);
}

// fp32 -> bf16 flat cast. n multiple of 1024.
__global__ __launch_bounds__(256)
void cast_kernel(const float* __restrict__ src, bf16* __restrict__ dst, int n)
{
  int i = (blockIdx.x * 256 + threadIdx.x) * 4;
  if (i < n) {
    float4 v = *(const float4*)(src + i);
    *(uint2*)((u32*)dst + i / 2) = make_uint2(f2bf2(v.x, v.y), f2bf2(v.z, v.w));
  }
}

// bf16 -> fp32 upcast (final c_kv output write). n multiple of 1024.
__global__ __launch_bounds__(256)
void upcast_kernel(const bf16* __restrict__ src, float* __restrict__ dst, int n)
{
  int i = (blockIdx.x * 256 + threadIdx.x) * 4;
  if (i < n) {
    uint2 v = *(const uint2*)((const u32*)src + i / 2);
    float4 o;
    o.x = __uint_as_float(v.x << 16);
    o.y = __uint_as_float(v.x & 0xffff0000u);
    o.z = __uint_as_float(v.y << 16);
    o.w = __uint_as_float(v.y & 0xffff0000u);
    *(float4*)(dst + i) = o;
  }
}

// fp32 [R][C] -> bf16 [C][R] transpose-cast. R,C multiples of 32.
__global__ __launch_bounds__(256)
void tcast_kernel(const float* __restrict__ src, bf16* __restrict__ dst,
                  int R, int C)
{
  __shared__ float s[32][33];
  const int r0 = blockIdx.x * 32, c0 = blockIdx.y * 32;
  const int x = threadIdx.x & 31, y = threadIdx.x >> 5;   // y: 0..7
#pragma unroll
  for (int i = 0; i < 4; ++i)
    s[y*4 + i][x] = src[(long)(r0 + y*4 + i) * C + c0 + x];
  __syncthreads();
  unsigned short* dp = (unsigned short*)dst;
#pragma unroll
  for (int i = 0; i < 4; ++i)
    dp[(long)(c0 + y*4 + i) * R + r0 + x] = f2bf(s[x][y*4 + i]);
}

// ckv [b][2048][512] -> ckvT [b][512][2048] (bf16).
__global__ __launch_bounds__(256)
void transpose_ckv(const bf16* __restrict__ src, bf16* __restrict__ dst)
{
  __shared__ unsigned short s[32][33];
  const int b = blockIdx.z, t0 = blockIdx.x * 32, l0 = blockIdx.y * 32;
  const int x = threadIdx.x & 31, y = threadIdx.x >> 5;
  const unsigned short* sp = (const unsigned short*)(src + (long)b * kT * kL);
  unsigned short* dp = (unsigned short*)(dst + (long)b * kL * kT);
#pragma unroll
  for (int i = 0; i < 4; ++i)
    s[y*4 + i][x] = sp[(long)(t0 + y*4 + i) * kL + l0 + x];
  __syncthreads();
#pragma unroll
  for (int i = 0; i < 4; ++i)
    dp[(long)(l0 + y*4 + i) * kT + t0 + x] = s[x][y*4 + i];
}

// ---------------------------------------------------------------------------
// NT MFMA GEMM (round-3 proven): C[m][n] = alpha * sum_k A[m][k] * B[n][k].
// ---------------------------------------------------------------------------
template<typename TCe>
__global__ __launch_bounds__(256)
void mm_nt(const bf16* __restrict__ A, int lda, long aHi, long aLo,
           const bf16* __restrict__ Bm, int ldb, long bHi, long bLo,
           TCe* __restrict__ Cm, int ldc, long cHi, long cLo,
           int K, float alpha)
{
  const int z = blockIdx.z;
  A  += (long)(z >> 4) * aHi + (long)(z & 15) * aLo;
  Bm += (long)(z >> 4) * bHi + (long)(z & 15) * bLo;
  Cm += (long)(z >> 4) * cHi + (long)(z & 15) * cLo;

  __shared__ __align__(16) bf16 As[64][72];
  __shared__ __align__(16) bf16 Bs[64][72];

  const int tid = threadIdx.x;
  const int w = tid >> 6, lane = tid & 63;
  const int quad = lane >> 4, lp = lane & 15;
  const int m0 = blockIdx.x * 64, n0 = blockIdx.y * 64;
  const int row = tid >> 2, cseg = (tid & 3) * 16;

  f4 acc[4];
#pragma unroll
  for (int i = 0; i < 4; ++i) acc[i] = f4{0.f, 0.f, 0.f, 0.f};

  for (int k0 = 0; k0 < K; k0 += 64) {
    const bf16* ag = A  + (long)(m0 + row) * lda + k0 + cseg;
    const bf16* bg = Bm + (long)(n0 + row) * ldb + k0 + cseg;
    uint4 a0 = *(const uint4*)ag, a1 = *(const uint4*)(ag + 8);
    uint4 b0 = *(const uint4*)bg, b1 = *(const uint4*)(bg + 8);
    __syncthreads();
    *(uint4*)&As[row][cseg] = a0; *(uint4*)&As[row][cseg + 8] = a1;
    *(uint4*)&Bs[row][cseg] = b0; *(uint4*)&Bs[row][cseg + 8] = b1;
    __syncthreads();

    short8 af0 = frag_ld(&As[w*16 + lp][quad * 8]);
    short8 af1 = frag_ld(&As[w*16 + lp][32 + quad * 8]);
#pragma unroll
    for (int nb = 0; nb < 4; ++nb) {
      short8 bf0 = frag_ld(&Bs[nb*16 + lp][quad * 8]);
      short8 bf1 = frag_ld(&Bs[nb*16 + lp][32 + quad * 8]);
      acc[nb] = __builtin_amdgcn_mfma_f32_16x16x32_bf16(af0, bf0, acc[nb], 0, 0, 0);
      acc[nb] = __builtin_amdgcn_mfma_f32_16x16x32_bf16(af1, bf1, acc[nb], 0, 0, 0);
    }
  }
#pragma unroll
  for (int nb = 0; nb < 4; ++nb)
#pragma unroll
    for (int r = 0; r < 4; ++r) {
      float v = alpha * acc[nb][r];
      long off = (long)(m0 + w*16 + quad*4 + r) * ldc + n0 + nb*16 + lp;
      if constexpr (__is_same(TCe, float)) Cm[off] = v;
      else ((unsigned short*)Cm)[off] = f2bf(v);
    }
}

// ---------------------------------------------------------------------------
// MFMA flash attention v4: DMA staging, no staging VGPRs.
// WG = 4 waves; wave w owns qb = 4*wgQ + w (16 queries). Stripe-pair balance.
// Ks[32][512]: phys block v of row r holds global block (v&~7)|((v^r)&7).
// KsT[512][32]: phys seg p of row rr holds global seg p ^ ((rr>>1)&3).
// ---------------------------------------------------------------------------
__global__ __launch_bounds__(256, 2)
void flash_mfma(bf16* __restrict__ qlat, const bf16* __restrict__ ckv,
                const bf16* __restrict__ ckvT)
{
  const int jj = blockIdx.x, h = blockIdx.y, b = blockIdx.z;
  const int tid = threadIdx.x;
  const int w = tid >> 6, lane = tid & 63;
  const int quad = lane >> 4, lp = lane & 15;

  __shared__ __align__(16) bf16 Ks[32 * 512];              // 32 KB
  __shared__ __align__(16) bf16 KsT[512 * 32];             // 32 KB
  __shared__ __align__(16) unsigned short Pbuf[4][16][40]; // 5 KB per-wave

  unsigned short (*Pw)[40] = Pbuf[w];
  u32* eb = (u32*)&Pbuf[w][0][0];                          // epilogue alias [16][20]

  const bf16* ckb = ckv  + (long)b * kT * kL;
  const bf16* ckt = ckvT + (long)b * kL * kT;

  // per-lane staging source offsets (constant over rounds, element units)
  int ksBlk[8], ktRow[8];
#pragma unroll
  for (int i = 0; i < 8; ++i) {
    int r = w * 8 + i;                              // Ks row 0..31
    ksBlk[i] = r * 512 + ((lane & ~7) | ((lane ^ r) & 7)) * 8; // src elem off in 32xkL tile... (row r, swizzled block)
    ktRow[i] = (w * 8 + i) * 16 + (lane >> 2);      // KsT row 0..511
  }
  const int ktSeg = ((lane & 3) ^ ((lane >> 3) & 3)) * 8;   // swizzled seg offset

  for (int half = 0; half < 2; ++half) {
    const int wgQ = half ? (31 - jj) : jj;
    const int qb = 4 * wgQ + w, q0 = qb * 16;
    bf16* qbase = qlat + (((long)(b * kNH + h)) * kT + q0) * kL;

    // persistent Q fragments (B-operand form): Q[q=lp][lb*32 + quad*8 + j]
    short8 qf[16];
#pragma unroll
    for (int lb = 0; lb < 16; ++lb)
      qf[lb] = frag_ld(qbase + (long)lp * kL + lb * 32 + quad * 8);

    f4 O[32];
#pragma unroll
    for (int ct = 0; ct < 32; ++ct) O[ct] = f4{0.f, 0.f, 0.f, 0.f};
    float m_r = -3e38f, l_r = 0.f;

    const int tmax = qb >> 1;
    const int nt = 2 * wgQ + 2;

    for (int t = 0; t < nt; ++t) {
      __syncthreads();                       // prev round's compute done
      { // DMA staging: 16 instrs/wave, zero VGPR round-trip
        const bf16* kbase = ckb + (long)t * 32 * kL;     // note: ksBlk has row*512 but rows are kL=512 apart -> row*kL == row*512 ✓
        const bf16* tbase = ckt + (long)t * 32 + ktSeg;
#pragma unroll
        for (int i = 0; i < 8; ++i) {
          g2lds16(kbase + ksBlk[i], &Ks[(w * 8 + i) * 512]);
          g2lds16(tbase + (long)ktRow[i] * kT, &KsT[(w * 8 + i) * 512]);
        }
      }
      __syncthreads();                       // vmcnt(0) drain + barrier
      if (t > tmax) continue;

      // ---- S^T = K * Q^T : two 16-key m-tiles ----
      f4 s0 = f4{0.f,0.f,0.f,0.f}, s1 = f4{0.f,0.f,0.f,0.f};
#pragma unroll
      for (int lb = 0; lb < 16; ++lb) {
        int u = lb * 4 + quad;
        int us8a = ((u & ~7) | ((u ^ lp) & 7)) * 8;          // row lp
        int us8b = ((u & ~7) | ((u ^ (16 + lp)) & 7)) * 8;   // row 16+lp
        short8 a0 = frag_ld(&Ks[lp * 512 + us8a]);
        short8 a1 = frag_ld(&Ks[(16 + lp) * 512 + us8b]);
        s0 = __builtin_amdgcn_mfma_f32_16x16x32_bf16(a0, qf[lb], s0, 0, 0, 0);
        s1 = __builtin_amdgcn_mfma_f32_16x16x32_bf16(a1, qf[lb], s1, 0, 0, 0);
      }

      // ---- causal mask: key = t*32 + chain*16 + quad*4 + r, q = q0 + lp ----
      if (t == tmax) {
        const int k0 = t * 32, q = q0 + lp;
#pragma unroll
        for (int r = 0; r < 4; ++r) {
          if (k0 + quad * 4 + r > q)      s0[r] = -3e38f;
          if (k0 + 16 + quad * 4 + r > q) s1[r] = -3e38f;
        }
      }

      // ---- online softmax (lane-local q; 2 shfl levels) ----
      float mold = m_r;
      float tm = fmaxf(fmaxf(fmaxf(s0[0], s0[1]), fmaxf(s0[2], s0[3])),
                       fmaxf(fmaxf(s1[0], s1[1]), fmaxf(s1[2], s1[3])));
      tm = fmaxf(tm, __shfl_xor(tm, 16, 64));
      tm = fmaxf(tm, __shfl_xor(tm, 32, 64));
      float mn = fmaxf(mold, tm);
      bool upd = mn > mold;
      float al = exp2f(mold - mn);
      float p0[4], p1[4], rs = 0.f;
#pragma unroll
      for (int r = 0; r < 4; ++r) {
        p0[r] = exp2f(s0[r] - mn);
        p1[r] = exp2f(s1[r] - mn);
        rs += p0[r] + p1[r];
      }
      rs += __shfl_xor(rs, 16, 64);
      rs += __shfl_xor(rs, 32, 64);
      l_r = l_r * al + rs;
      m_r = mn;

      // ---- P^T -> per-wave LDS [q=lp][key], read back as B-frag ----
      *(uint2*)&Pw[lp][quad * 4] =
          make_uint2(f2bf2(p0[0], p0[1]), f2bf2(p0[2], p0[3]));
      *(uint2*)&Pw[lp][16 + quad * 4] =
          make_uint2(f2bf2(p1[0], p1[1]), f2bf2(p1[2], p1[3]));
      asm volatile("s_waitcnt lgkmcnt(0)" ::: "memory");
      short8 pb = frag_ld(&Pw[lp][quad * 8]);

      // ---- rescale O^T (lane-local alpha) ----
      if (__ballot(upd)) {
#pragma unroll
        for (int ct = 0; ct < 32; ++ct) {
          O[ct][0] *= al; O[ct][1] *= al; O[ct][2] *= al; O[ct][3] *= al;
        }
      }

      // ---- PV: O^T[lat][q] += V^T * P^T, A-frags from swizzled KsT ----
      const int pseg = (quad ^ ((lp >> 1) & 3)) * 8;
#pragma unroll
      for (int ct = 0; ct < 32; ++ct) {
        short8 a = frag_ld(&KsT[(ct * 16 + lp) * 32 + pseg]);
        O[ct] = __builtin_amdgcn_mfma_f32_16x16x32_bf16(a, pb, O[ct], 0, 0, 0);
      }
    }

    // ---- epilogue: inv lane-local; transpose O^T via LDS slice; store ----
    {
      float inv = 1.0f / l_r;
      for (int cc = 0; cc < 16; ++cc) {
#pragma unroll
        for (int i = 0; i < 2; ++i) {
          int ct = cc * 2 + i;
          *(uint2*)&eb[lp * 20 + i * 8 + quad * 2] =
              make_uint2(f2bf2(O[ct][0] * inv, O[ct][1] * inv),
                         f2bf2(O[ct][2] * inv, O[ct][3] * inv));
        }
        asm volatile("s_waitcnt lgkmcnt(0)" ::: "memory");
        int qrow = lane >> 2, seg = lane & 3;
        uint4 v = *(const uint4*)&eb[qrow * 20 + seg * 4];
        *(uint4*)(qbase + (long)qrow * kL + cc * 32 + seg * 8) = v;
        asm volatile("s_waitcnt lgkmcnt(0)" ::: "memory");
      }
    }
  }
}

// ---------------------------------------------------------------------------
extern "C" void kernel_launch(void* const* d_in, const int* in_sizes, int n_in,
                              void* d_out, int out_size, void* d_ws, size_t ws_size,
                              hipStream_t stream)
{
  const float* x     = (const float*)d_in[0];
  const float* W_dq  = (const float*)d_in[1];
  const float* W_uq  = (const float*)d_in[2];
  const float* W_dkv = (const float*)d_in[3];
  const float* W_uk  = (const float*)d_in[4];
  const float* W_uv  = (const float*)d_in[5];
  const float* W_o   = (const float*)d_in[6];

  float* y_out   = (float*)d_out;
  float* ckv_out = y_out + (long)kB * kT * kC;

  // workspace layout (max 101,711,872 B, proven bound)
  char* ws = (char*)d_ws;
  bf16* q_lat  = (bf16*)(ws + 0);            // 64 MB  (y_lat in place)
  bf16* ckv_b  = (bf16*)(ws + 67108864);     //  4 MB
  bf16* ckvT   = (bf16*)(ws + 71303168);     //  4 MB
  bf16* xb     = (bf16*)(ws + 75497472);     //  8 MB
  bf16* q_lowb = (bf16*)(ws + 83886080);     //  4 MB
  bf16* qfullb = (bf16*)(ws + 88080384);     //  8 MB (scratch overlap below)
  bf16* W_uqTb = (bf16*)(ws + 88080384);     //  1 MB  [dead before qfullb write]
  bf16* W_ukTb = (bf16*)(ws + 89128960);     //  1 MB
  bf16* W_uvTb = (bf16*)(ws + 90177536);     //  1 MB
  bf16* W_dqTb = (bf16*)(ws + 91226112);     //  1 MB
  bf16* W_ob   = (bf16*)(ws + 92274688);     //  2 MB
  bf16* tmpT   = (bf16*)(ws + 94371840);     // 0.5 MB
  bf16* k_effT = (bf16*)(ws + 96468992);     //  1 MB  [512 l][1024 c]
  bf16* v_effT = (bf16*)(ws + 97517568);     //  1 MB  [1024 j][512 l]
  bf16* W_dqb  = (bf16*)(ws + 98566144);     //  1 MB
  bf16* W_uqb  = (bf16*)(ws + 99614720);     //  1 MB
  bf16* W_dkvb = (bf16*)(ws + 100663296);    //  1 MB

  const dim3 blk(256);
  const long TC = (long)kT * kC, TL = (long)kT * kL;
  const float kScale = 0.125f * 1.44269504088896f;   // 1/sqrt(hs) * log2(e)

  cast_kernel<<<dim3(4096), blk, 0, stream>>>(x,     xb,     4194304);
  cast_kernel<<<dim3(512),  blk, 0, stream>>>(W_dq,  W_dqb,  524288);
  cast_kernel<<<dim3(512),  blk, 0, stream>>>(W_uq,  W_uqb,  524288);
  cast_kernel<<<dim3(512),  blk, 0, stream>>>(W_dkv, W_dkvb, 524288);
  cast_kernel<<<dim3(1024), blk, 0, stream>>>(W_o,   W_ob,   1048576);
  tcast_kernel<<<dim3(32, 16), blk, 0, stream>>>(W_uq, W_uqTb, 1024, 512);
  tcast_kernel<<<dim3(32, 16), blk, 0, stream>>>(W_uk, W_ukTb, 1024, 512);
  tcast_kernel<<<dim3(32, 16), blk, 0, stream>>>(W_uv, W_uvTb, 1024, 512);
  tcast_kernel<<<dim3(16, 32), blk, 0, stream>>>(W_dq, W_dqTb, 512, 1024);

  mm_nt<bf16><<<dim3(8, 8, 1), blk, 0, stream>>>(
      W_ukTb, 1024, 0, 0, W_uqTb, 1024, 0, 0, tmpT, 512, 0, 0, 1024, 1.0f);
  mm_nt<bf16><<<dim3(8, 16, 1), blk, 0, stream>>>(
      tmpT, 512, 0, 0, W_dqTb, 512, 0, 0, k_effT, 1024, 0, 0, 512, kScale);
  mm_nt<bf16><<<dim3(16, 8, 1), blk, 0, stream>>>(
      W_ob, 1024, 0, 0, W_uvTb, 1024, 0, 0, v_effT, 512, 0, 0, 1024, 1.0f);
  mm_nt<bf16><<<dim3(64, 8, 1), blk, 0, stream>>>(
      xb, 1024, 0, 0, W_dqb, 1024, 0, 0, q_lowb, 512, 0, 0, 1024, 1.0f);
  mm_nt<bf16><<<dim3(64, 16, 1), blk, 0, stream>>>(
      q_lowb, 512, 0, 0, W_uqb, 512, 0, 0, qfullb, 1024, 0, 0, 512, 1.0f);
  // c_kv -> bf16 ckv_b directly (no early d_out write)
  mm_nt<bf16><<<dim3(64, 8, 1), blk, 0, stream>>>(
      xb, 1024, 0, 0, W_dkvb, 1024, 0, 0, ckv_b, 512, 0, 0, 1024, 1.0f);
  transpose_ckv<<<dim3(64, 16, 2), blk, 0, stream>>>(ckv_b, ckvT);
  mm_nt<bf16><<<dim3(32, 8, 32), blk, 0, stream>>>(
      qfullb, 1024, TC, 64,
      k_effT, 1024, 0, 64,
      q_lat, 512, (long)kNH * TL, TL,
      64, 1.0f);
  flash_mfma<<<dim3(16, 16, 2), blk, 0, stream>>>(q_lat, ckv_b, ckvT);
  mm_nt<float><<<dim3(32, 1, 32), blk, 0, stream>>>(
      q_lat, 512, (long)kNH * TL, TL,
      v_effT, 512, 0, (long)64 * 512,
      y_out, 1024, TC, 64,
      512, 1.0f);
  // FINAL kernel: write the fp32 c_kv output tail last.
  upcast_kernel<<<dim3(2048), blk, 0, stream>>>(ckv_b, ckv_out, 2097152);

  (void)in_sizes; (void)n_in; (void)out_size; (void)ws_size;
}

// Round 8
// 437.676 us; speedup vs baseline: 17.7419x; 1.0625x over previous
//
#include <hip/hip_runtime.h>
#include <hip/hip_bf16.h>

// MLA absorbed causal attention, MI355X round 7:
//  flash v5: one 512-thread WG/CU, double-buffered DMA staging
//  (global_load_lds), ONE barrier per round with drain hidden behind compute.
//  Prologue casts fused into 2 kernels.
// fp32 I/O. d_out = [ y (2*2048*1024) | c_kv (2*2048*512) ] fp32.

using bf16 = __hip_bfloat16;
using u32  = unsigned int;
using short8 = __attribute__((ext_vector_type(8))) short;   // 8 bf16 (4 VGPRs)
using f4     = __attribute__((ext_vector_type(4))) float;   // MFMA accumulator

static constexpr int kB  = 2;
static constexpr int kT  = 2048;
static constexpr int kC  = 1024;
static constexpr int kNH = 16;
static constexpr int kL  = 512;

__device__ inline u32 f2bf2(float a, float b) {
  bf16 ha = __float2bfloat16(a), hb = __float2bfloat16(b);
  unsigned short ua, ub;
  __builtin_memcpy(&ua, &ha, 2);
  __builtin_memcpy(&ub, &hb, 2);
  return (u32)ua | ((u32)ub << 16);
}
__device__ inline unsigned short f2bf(float x) {
  bf16 h = __float2bfloat16(x);
  unsigned short u; __builtin_memcpy(&u, &h, 2);
  return u;
}
__device__ inline short8 frag_ld(const void* p) {   // 16B aligned -> ds/global b128
  short8 r; __builtin_memcpy(&r, p, 16); return r;
}
// async global->LDS DMA, 16 B/lane. dest = wave-uniform base + lane*16.
__device__ inline void g2lds16(const bf16* g, bf16* l) {
  __builtin_amdgcn_global_load_lds(
      (const __attribute__((address_space(1))) u32*)g,
      (__attribute__((address_space(3))) u32*)l, 16, 0, 0);
}

// ---- fused flat casts: x, W_dq, W_uq, W_dkv, W_o -> bf16 ----
__global__ __launch_bounds__(256)
void casts_all(const float* __restrict__ x,   const float* __restrict__ wdq,
               const float* __restrict__ wuq, const float* __restrict__ wdkv,
               const float* __restrict__ wo,
               bf16* __restrict__ xb,   bf16* __restrict__ wdqb,
               bf16* __restrict__ wuqb, bf16* __restrict__ wdkvb,
               bf16* __restrict__ wob)
{
  long i = (long)(blockIdx.x * 256 + threadIdx.x) * 4;
  const float* s; bf16* d; long off;
  if      (i < 4194304) { s = x;    d = xb;    off = i; }
  else if (i < 4718592) { s = wdq;  d = wdqb;  off = i - 4194304; }
  else if (i < 5242880) { s = wuq;  d = wuqb;  off = i - 4718592; }
  else if (i < 5767168) { s = wdkv; d = wdkvb; off = i - 5242880; }
  else                  { s = wo;   d = wob;   off = i - 5767168; }
  float4 v = *(const float4*)(s + off);
  *(uint2*)((u32*)d + off / 2) = make_uint2(f2bf2(v.x, v.y), f2bf2(v.z, v.w));
}

// bf16 -> fp32 upcast (final c_kv output write). n multiple of 1024.
__global__ __launch_bounds__(256)
void upcast_kernel(const bf16* __restrict__ src, float* __restrict__ dst, int n)
{
  int i = (blockIdx.x * 256 + threadIdx.x) * 4;
  if (i < n) {
    uint2 v = *(const uint2*)((const u32*)src + i / 2);
    float4 o;
    o.x = __uint_as_float(v.x << 16);
    o.y = __uint_as_float(v.x & 0xffff0000u);
    o.z = __uint_as_float(v.y << 16);
    o.w = __uint_as_float(v.y & 0xffff0000u);
    *(float4*)(dst + i) = o;
  }
}

// ---- fused transpose-casts: z selects (src,dst,R,C); guards for shape ----
__global__ __launch_bounds__(256)
void tcasts_all(const float* __restrict__ wuq, const float* __restrict__ wuk,
                const float* __restrict__ wuv, const float* __restrict__ wdq,
                bf16* __restrict__ uqT, bf16* __restrict__ ukT,
                bf16* __restrict__ uvT, bf16* __restrict__ dqT)
{
  const int z = blockIdx.z;
  const float* src = z == 0 ? wuq : z == 1 ? wuk : z == 2 ? wuv : wdq;
  bf16* dst        = z == 0 ? uqT : z == 1 ? ukT : z == 2 ? uvT : dqT;
  const int R = (z == 3) ? 512 : 1024, C = (z == 3) ? 1024 : 512;
  const int r0 = blockIdx.x * 32, c0 = blockIdx.y * 32;
  if (r0 >= R || c0 >= C) return;
  __shared__ float s[32][33];
  const int x = threadIdx.x & 31, y = threadIdx.x >> 5;   // y: 0..7
#pragma unroll
  for (int i = 0; i < 4; ++i)
    s[y*4 + i][x] = src[(long)(r0 + y*4 + i) * C + c0 + x];
  __syncthreads();
  unsigned short* dp = (unsigned short*)dst;
#pragma unroll
  for (int i = 0; i < 4; ++i)
    dp[(long)(c0 + y*4 + i) * R + r0 + x] = f2bf(s[x][y*4 + i]);
}

// ckv [b][2048][512] -> ckvT [b][512][2048] (bf16).
__global__ __launch_bounds__(256)
void transpose_ckv(const bf16* __restrict__ src, bf16* __restrict__ dst)
{
  __shared__ unsigned short s[32][33];
  const int b = blockIdx.z, t0 = blockIdx.x * 32, l0 = blockIdx.y * 32;
  const int x = threadIdx.x & 31, y = threadIdx.x >> 5;
  const unsigned short* sp = (const unsigned short*)(src + (long)b * kT * kL);
  unsigned short* dp = (unsigned short*)(dst + (long)b * kL * kT);
#pragma unroll
  for (int i = 0; i < 4; ++i)
    s[y*4 + i][x] = sp[(long)(t0 + y*4 + i) * kL + l0 + x];
  __syncthreads();
#pragma unroll
  for (int i = 0; i < 4; ++i)
    dp[(long)(l0 + y*4 + i) * kT + t0 + x] = s[x][y*4 + i];
}

// ---------------------------------------------------------------------------
// NT MFMA GEMM (round-3 proven): C[m][n] = alpha * sum_k A[m][k] * B[n][k].
// ---------------------------------------------------------------------------
template<typename TCe>
__global__ __launch_bounds__(256)
void mm_nt(const bf16* __restrict__ A, int lda, long aHi, long aLo,
           const bf16* __restrict__ Bm, int ldb, long bHi, long bLo,
           TCe* __restrict__ Cm, int ldc, long cHi, long cLo,
           int K, float alpha)
{
  const int z = blockIdx.z;
  A  += (long)(z >> 4) * aHi + (long)(z & 15) * aLo;
  Bm += (long)(z >> 4) * bHi + (long)(z & 15) * bLo;
  Cm += (long)(z >> 4) * cHi + (long)(z & 15) * cLo;

  __shared__ __align__(16) bf16 As[64][72];
  __shared__ __align__(16) bf16 Bs[64][72];

  const int tid = threadIdx.x;
  const int w = tid >> 6, lane = tid & 63;
  const int quad = lane >> 4, lp = lane & 15;
  const int m0 = blockIdx.x * 64, n0 = blockIdx.y * 64;
  const int row = tid >> 2, cseg = (tid & 3) * 16;

  f4 acc[4];
#pragma unroll
  for (int i = 0; i < 4; ++i) acc[i] = f4{0.f, 0.f, 0.f, 0.f};

  for (int k0 = 0; k0 < K; k0 += 64) {
    const bf16* ag = A  + (long)(m0 + row) * lda + k0 + cseg;
    const bf16* bg = Bm + (long)(n0 + row) * ldb + k0 + cseg;
    uint4 a0 = *(const uint4*)ag, a1 = *(const uint4*)(ag + 8);
    uint4 b0 = *(const uint4*)bg, b1 = *(const uint4*)(bg + 8);
    __syncthreads();
    *(uint4*)&As[row][cseg] = a0; *(uint4*)&As[row][cseg + 8] = a1;
    *(uint4*)&Bs[row][cseg] = b0; *(uint4*)&Bs[row][cseg + 8] = b1;
    __syncthreads();

    short8 af0 = frag_ld(&As[w*16 + lp][quad * 8]);
    short8 af1 = frag_ld(&As[w*16 + lp][32 + quad * 8]);
#pragma unroll
    for (int nb = 0; nb < 4; ++nb) {
      short8 bf0 = frag_ld(&Bs[nb*16 + lp][quad * 8]);
      short8 bf1 = frag_ld(&Bs[nb*16 + lp][32 + quad * 8]);
      acc[nb] = __builtin_amdgcn_mfma_f32_16x16x32_bf16(af0, bf0, acc[nb], 0, 0, 0);
      acc[nb] = __builtin_amdgcn_mfma_f32_16x16x32_bf16(af1, bf1, acc[nb], 0, 0, 0);
    }
  }
#pragma unroll
  for (int nb = 0; nb < 4; ++nb)
#pragma unroll
    for (int r = 0; r < 4; ++r) {
      float v = alpha * acc[nb][r];
      long off = (long)(m0 + w*16 + quad*4 + r) * ldc + n0 + nb*16 + lp;
      if constexpr (__is_same(TCe, float)) Cm[off] = v;
      else ((unsigned short*)Cm)[off] = f2bf(v);
    }
}

// ---------------------------------------------------------------------------
// MFMA flash attention v5: 512-thread WG (8 waves), double-buffered DMA
// staging, one barrier per round (drain hidden behind compute).
// Wave w owns qb = 8*stripe + w (16 queries). Stripes pair j / 15-j: every
// WG does 68 rounds. Grid (8,16,2) = 256 WGs = 1/CU (LDS 138 KB).
// Ks[32][512]: phys 16B-block v of row r holds global block (v&~7)|((v^r)&7).
// KsT[512][32]: phys seg p of row rr holds global seg p ^ ((rr>>1)&3).
// ---------------------------------------------------------------------------
__global__ __launch_bounds__(512, 2)
void flash_mfma(bf16* __restrict__ qlat, const bf16* __restrict__ ckv,
                const bf16* __restrict__ ckvT)
{
  const int jj = blockIdx.x, h = blockIdx.y, b = blockIdx.z;
  const int tid = threadIdx.x;
  const int w = tid >> 6, lane = tid & 63;
  const int quad = lane >> 4, lp = lane & 15;

  __shared__ __align__(16) bf16 Ks[2][32 * 512];           // 64 KB
  __shared__ __align__(16) bf16 KsT[2][512 * 32];          // 64 KB
  __shared__ __align__(16) unsigned short Pbuf[8][16][40]; // 10 KB per-wave

  unsigned short (*Pw)[40] = Pbuf[w];
  u32* eb = (u32*)&Pbuf[w][0][0];                          // epilogue alias [16][20]

  const bf16* ckb = ckv  + (long)b * kT * kL;
  const bf16* ckt = ckvT + (long)b * kL * kT;

  // per-lane staging constants (element units)
  int ksOff[4], ktRow[4];
#pragma unroll
  for (int i = 0; i < 4; ++i) {
    int r = w * 4 + i;                              // Ks row 0..31
    ksOff[i] = r * 512 + ((lane & ~7) | ((lane ^ r) & 7)) * 8;
    ktRow[i] = (w * 4 + i) * 16 + (lane >> 2);      // KsT row 0..511
  }
  const int ktSeg = ((lane & 3) ^ ((lane >> 3) & 3)) * 8;   // (g*8)%4==0 -> lane-only

  for (int half = 0; half < 2; ++half) {
    const int stripe = half ? (15 - jj) : jj;
    const int qb = 8 * stripe + w, q0 = qb * 16;
    bf16* qbase = qlat + (((long)(b * kNH + h)) * kT + q0) * kL;

    // persistent Q fragments (B-operand form): Q[q=lp][lb*32 + quad*8 + j]
    short8 qf[16];
#pragma unroll
    for (int lb = 0; lb < 16; ++lb)
      qf[lb] = frag_ld(qbase + (long)lp * kL + lb * 32 + quad * 8);

    f4 O[32];
#pragma unroll
    for (int ct = 0; ct < 32; ++ct) O[ct] = f4{0.f, 0.f, 0.f, 0.f};
    float m_r = -3e38f, l_r = 0.f;

    const int tmax = qb >> 1;
    const int nt = 4 * stripe + 4;

    // prologue: stage tile 0 into buffer 0
    {
      const bf16* kbase = ckb;                 // t = 0
      const bf16* tbase = ckt + ktSeg;
#pragma unroll
      for (int i = 0; i < 4; ++i) {
        g2lds16(kbase + ksOff[i], &Ks[0][(w * 4 + i) * 512]);
        g2lds16(tbase + (long)ktRow[i] * kT, &KsT[0][(w * 4 + i) * 512]);
      }
    }
    __syncthreads();

    for (int t = 0; t < nt; ++t) {
      const int bf = t & 1;
      if (t + 1 < nt) {                        // stage t+1 into other buffer
        const bf16* kbase = ckb + (long)(t + 1) * 32 * kL;
        const bf16* tbase = ckt + (long)(t + 1) * 32 + ktSeg;
#pragma unroll
        for (int i = 0; i < 4; ++i) {
          g2lds16(kbase + ksOff[i], &Ks[bf ^ 1][(w * 4 + i) * 512]);
          g2lds16(tbase + (long)ktRow[i] * kT, &KsT[bf ^ 1][(w * 4 + i) * 512]);
        }
      }

      if (t <= tmax) {
        // ---- S^T = K * Q^T : two 16-key m-tiles ----
        const bf16* KsB = Ks[bf];
        f4 s0 = f4{0.f,0.f,0.f,0.f}, s1 = f4{0.f,0.f,0.f,0.f};
#pragma unroll
        for (int lb = 0; lb < 16; ++lb) {
          int u = lb * 4 + quad;
          int us8a = ((u & ~7) | ((u ^ lp) & 7)) * 8;          // row lp
          int us8b = ((u & ~7) | ((u ^ (16 + lp)) & 7)) * 8;   // row 16+lp
          short8 a0 = frag_ld(&KsB[lp * 512 + us8a]);
          short8 a1 = frag_ld(&KsB[(16 + lp) * 512 + us8b]);
          s0 = __builtin_amdgcn_mfma_f32_16x16x32_bf16(a0, qf[lb], s0, 0, 0, 0);
          s1 = __builtin_amdgcn_mfma_f32_16x16x32_bf16(a1, qf[lb], s1, 0, 0, 0);
        }

        // ---- causal mask: key = t*32 + chain*16 + quad*4 + r, q = q0+lp ----
        if (t == tmax) {
          const int k0 = t * 32, q = q0 + lp;
#pragma unroll
          for (int r = 0; r < 4; ++r) {
            if (k0 + quad * 4 + r > q)      s0[r] = -3e38f;
            if (k0 + 16 + quad * 4 + r > q) s1[r] = -3e38f;
          }
        }

        // ---- online softmax (lane-local q; 2 shfl levels) ----
        float mold = m_r;
        float tm = fmaxf(fmaxf(fmaxf(s0[0], s0[1]), fmaxf(s0[2], s0[3])),
                         fmaxf(fmaxf(s1[0], s1[1]), fmaxf(s1[2], s1[3])));
        tm = fmaxf(tm, __shfl_xor(tm, 16, 64));
        tm = fmaxf(tm, __shfl_xor(tm, 32, 64));
        float mn = fmaxf(mold, tm);
        bool upd = mn > mold;
        float al = exp2f(mold - mn);
        float p0[4], p1[4], rs = 0.f;
#pragma unroll
        for (int r = 0; r < 4; ++r) {
          p0[r] = exp2f(s0[r] - mn);
          p1[r] = exp2f(s1[r] - mn);
          rs += p0[r] + p1[r];
        }
        rs += __shfl_xor(rs, 16, 64);
        rs += __shfl_xor(rs, 32, 64);
        l_r = l_r * al + rs;
        m_r = mn;

        // ---- P^T -> per-wave LDS [q=lp][key], read back as B-frag ----
        *(uint2*)&Pw[lp][quad * 4] =
            make_uint2(f2bf2(p0[0], p0[1]), f2bf2(p0[2], p0[3]));
        *(uint2*)&Pw[lp][16 + quad * 4] =
            make_uint2(f2bf2(p1[0], p1[1]), f2bf2(p1[2], p1[3]));
        asm volatile("s_waitcnt lgkmcnt(0)" ::: "memory");
        short8 pb = frag_ld(&Pw[lp][quad * 8]);

        // ---- rescale O^T (lane-local alpha) ----
        if (__ballot(upd)) {
#pragma unroll
          for (int ct = 0; ct < 32; ++ct) {
            O[ct][0] *= al; O[ct][1] *= al; O[ct][2] *= al; O[ct][3] *= al;
          }
        }

        // ---- PV: O^T[lat][q] += V^T * P^T, A-frags from swizzled KsT ----
        const bf16* KtB = KsT[bf];
        const int pseg = (quad ^ ((lp >> 1) & 3)) * 8;
#pragma unroll
        for (int ct = 0; ct < 32; ++ct) {
          short8 a = frag_ld(&KtB[(ct * 16 + lp) * 32 + pseg]);
          O[ct] = __builtin_amdgcn_mfma_f32_16x16x32_bf16(a, pb, O[ct], 0, 0, 0);
        }
      }
      __syncthreads();   // closes round: buffers reusable; DMA t+1 drained here
    }

    // ---- epilogue: inv lane-local; transpose O^T via LDS slice; store ----
    {
      float inv = 1.0f / l_r;
      for (int cc = 0; cc < 16; ++cc) {
#pragma unroll
        for (int i = 0; i < 2; ++i) {
          int ct = cc * 2 + i;
          *(uint2*)&eb[lp * 20 + i * 8 + quad * 2] =
              make_uint2(f2bf2(O[ct][0] * inv, O[ct][1] * inv),
                         f2bf2(O[ct][2] * inv, O[ct][3] * inv));
        }
        asm volatile("s_waitcnt lgkmcnt(0)" ::: "memory");
        int qrow = lane >> 2, seg = lane & 3;
        uint4 v = *(const uint4*)&eb[qrow * 20 + seg * 4];
        *(uint4*)(qbase + (long)qrow * kL + cc * 32 + seg * 8) = v;
        asm volatile("s_waitcnt lgkmcnt(0)" ::: "memory");
      }
    }
    __syncthreads();     // half boundary: epilogue done before next prologue DMA
  }
}

// ---------------------------------------------------------------------------
extern "C" void kernel_launch(void* const* d_in, const int* in_sizes, int n_in,
                              void* d_out, int out_size, void* d_ws, size_t ws_size,
                              hipStream_t stream)
{
  const float* x     = (const float*)d_in[0];
  const float* W_dq  = (const float*)d_in[1];
  const float* W_uq  = (const float*)d_in[2];
  const float* W_dkv = (const float*)d_in[3];
  const float* W_uk  = (const float*)d_in[4];
  const float* W_uv  = (const float*)d_in[5];
  const float* W_o   = (const float*)d_in[6];

  float* y_out   = (float*)d_out;
  float* ckv_out = y_out + (long)kB * kT * kC;

  // workspace layout (max 101,711,872 B, proven bound)
  char* ws = (char*)d_ws;
  bf16* q_lat  = (bf16*)(ws + 0);            // 64 MB  (y_lat in place)
  bf16* ckv_b  = (bf16*)(ws + 67108864);     //  4 MB
  bf16* ckvT   = (bf16*)(ws + 71303168);     //  4 MB
  bf16* xb     = (bf16*)(ws + 75497472);     //  8 MB
  bf16* q_lowb = (bf16*)(ws + 83886080);     //  4 MB
  bf16* qfullb = (bf16*)(ws + 88080384);     //  8 MB (scratch overlap below)
  bf16* W_uqTb = (bf16*)(ws + 88080384);     //  1 MB  [dead before qfullb write]
  bf16* W_ukTb = (bf16*)(ws + 89128960);     //  1 MB
  bf16* W_uvTb = (bf16*)(ws + 90177536);     //  1 MB
  bf16* W_dqTb = (bf16*)(ws + 91226112);     //  1 MB
  bf16* W_ob   = (bf16*)(ws + 92274688);     //  2 MB
  bf16* tmpT   = (bf16*)(ws + 94371840);     // 0.5 MB
  bf16* k_effT = (bf16*)(ws + 96468992);     //  1 MB  [512 l][1024 c]
  bf16* v_effT = (bf16*)(ws + 97517568);     //  1 MB  [1024 j][512 l]
  bf16* W_dqb  = (bf16*)(ws + 98566144);     //  1 MB
  bf16* W_uqb  = (bf16*)(ws + 99614720);     //  1 MB
  bf16* W_dkvb = (bf16*)(ws + 100663296);    //  1 MB

  const dim3 blk(256);
  const long TC = (long)kT * kC, TL = (long)kT * kL;
  const float kScale = 0.125f * 1.44269504088896f;   // 1/sqrt(hs) * log2(e)

  casts_all<<<dim3(6656), blk, 0, stream>>>(
      x, W_dq, W_uq, W_dkv, W_o, xb, W_dqb, W_uqb, W_dkvb, W_ob);
  tcasts_all<<<dim3(32, 32, 4), blk, 0, stream>>>(
      W_uq, W_uk, W_uv, W_dq, W_uqTb, W_ukTb, W_uvTb, W_dqTb);

  mm_nt<bf16><<<dim3(8, 8, 1), blk, 0, stream>>>(
      W_ukTb, 1024, 0, 0, W_uqTb, 1024, 0, 0, tmpT, 512, 0, 0, 1024, 1.0f);
  mm_nt<bf16><<<dim3(8, 16, 1), blk, 0, stream>>>(
      tmpT, 512, 0, 0, W_dqTb, 512, 0, 0, k_effT, 1024, 0, 0, 512, kScale);
  mm_nt<bf16><<<dim3(16, 8, 1), blk, 0, stream>>>(
      W_ob, 1024, 0, 0, W_uvTb, 1024, 0, 0, v_effT, 512, 0, 0, 1024, 1.0f);
  mm_nt<bf16><<<dim3(64, 8, 1), blk, 0, stream>>>(
      xb, 1024, 0, 0, W_dqb, 1024, 0, 0, q_lowb, 512, 0, 0, 1024, 1.0f);
  mm_nt<bf16><<<dim3(64, 16, 1), blk, 0, stream>>>(
      q_lowb, 512, 0, 0, W_uqb, 512, 0, 0, qfullb, 1024, 0, 0, 512, 1.0f);
  // c_kv -> bf16 ckv_b directly (no early d_out write)
  mm_nt<bf16><<<dim3(64, 8, 1), blk, 0, stream>>>(
      xb, 1024, 0, 0, W_dkvb, 1024, 0, 0, ckv_b, 512, 0, 0, 1024, 1.0f);
  transpose_ckv<<<dim3(64, 16, 2), blk, 0, stream>>>(ckv_b, ckvT);
  mm_nt<bf16><<<dim3(32, 8, 32), blk, 0, stream>>>(
      qfullb, 1024, TC, 64,
      k_effT, 1024, 0, 64,
      q_lat, 512, (long)kNH * TL, TL,
      64, 1.0f);
  flash_mfma<<<dim3(8, 16, 2), dim3(512), 0, stream>>>(q_lat, ckv_b, ckvT);
  mm_nt<float><<<dim3(32, 1, 32), blk, 0, stream>>>(
      q_lat, 512, (long)kNH * TL, TL,
      v_effT, 512, 0, (long)64 * 512,
      y_out, 1024, TC, 64,
      512, 1.0f);
  // FINAL kernel: write the fp32 c_kv output tail last.
  upcast_kernel<<<dim3(2048), blk, 0, stream>>>(ckv_b, ckv_out, 2097152);

  (void)in_sizes; (void)n_in; (void)out_size; (void)ws_size;
}